// Round 4
// baseline (1132.740 us; speedup 1.0000x reference)
//
#include <hip/hip_runtime.h>
#include <hip/hip_bf16.h>

typedef __hip_bfloat16 bf16;

// MODE: 0 = f32 fixed, 1 = bf16 fixed, 2 = dynamic (input/output dtype per flags[1])
template <int MODE>
__device__ __forceinline__ float ld_m(const void* p, long long i, int dynbf) {
    if (MODE == 0) return ((const float*)p)[i];
    if (MODE == 1) return __bfloat162float(((const bf16*)p)[i]);
    return dynbf ? __bfloat162float(((const bf16*)p)[i]) : ((const float*)p)[i];
}
template <int MODE>
__device__ __forceinline__ void st_m(void* p, long long i, float v, int dynbf) {
    if (MODE == 0) { ((float*)p)[i] = v; return; }
    if (MODE == 1) { ((bf16*)p)[i] = __float2bfloat16(v); return; }
    if (dynbf) ((bf16*)p)[i] = __float2bfloat16(v);
    else       ((float*)p)[i] = v;
}

__device__ __forceinline__ float relu_keepnan(float v) { return (v <= 0.f) ? 0.f : v; }
__device__ __forceinline__ int clampi(int v, int lo, int hi) {
    return v < lo ? lo : (v > hi ? hi : v);
}

// ---- init: zero cnt/csr_row; detect edge int64 (flags[0]) and float bf16 (flags[1]) ----
__global__ void k_init(int* __restrict__ cnt, int n, int* __restrict__ csr_row, int E,
                       const int* __restrict__ ei, const unsigned* __restrict__ xw,
                       int* __restrict__ flags) {
    int i = blockIdx.x * blockDim.x + threadIdx.x;
    int stride = gridDim.x * blockDim.x;
    for (int j = i; j < n; j += stride) cnt[j] = 0;
    for (int j = i; j < E; j += stride) csr_row[j] = 0;
    if (blockIdx.x == 0 && threadIdx.x < 64) {
        int lane = threadIdx.x;
        // edge dtype: int64 LE values < 2^31 -> odd int32 words are all 0
        int ov = (lane < 16) ? ei[2 * lane + 1] : 0;
        unsigned long long be = __ballot(ov != 0);
        // float dtype: bits 14..7 of a word = bf16 exponent (concentrated for N(0,1) data)
        // if bf16-packed; uniform mantissa bits if true f32.
        int inb = 0;
        #pragma unroll
        for (int q = 0; q < 2; ++q) {
            unsigned w = xw[lane + 64 * q];
            int e = (w >> 7) & 0xFF;
            inb += (e >= 110 && e <= 131) ? 1 : 0;
        }
        #pragma unroll
        for (int o = 32; o; o >>= 1) inb += __shfl_down(inb, o, 64);
        if (lane == 0) {
            flags[0] = (be == 0ULL) ? 1 : 0;   // edges are int64
            flags[1] = (inb >= 64) ? 1 : 0;    // floats are bf16
        }
    }
}

__global__ void k_count(const int* __restrict__ ei, int* __restrict__ cnt,
                        int E, int n, const int* __restrict__ flags) {
    int e = blockIdx.x * blockDim.x + threadIdx.x;
    if (e >= E) return;
    bool i64 = flags[0] != 0;
    int c = ei[i64 ? 2LL * ((long long)E + e) : (long long)E + e];
    c = clampi(c, 0, n - 1);
    atomicAdd(&cnt[c], 1);
}

__global__ void k_scan_dis(const int* __restrict__ cnt, int* __restrict__ offs,
                           int* __restrict__ cursor, float* __restrict__ dis, int n) {
    __shared__ int ssum[1024];
    int t = threadIdx.x;
    int chunk = (n + 1023) / 1024;
    int lo = t * chunk;
    int hi = lo + chunk; if (hi > n) hi = n;
    int s = 0;
    for (int i = lo; i < hi; ++i) s += cnt[i];
    ssum[t] = s;
    __syncthreads();
    for (int o = 1; o < 1024; o <<= 1) {
        int v = (t >= o) ? ssum[t - o] : 0;
        __syncthreads();
        ssum[t] += v;
        __syncthreads();
    }
    int run = (t > 0) ? ssum[t - 1] : 0;
    for (int i = lo; i < hi; ++i) {
        int c = cnt[i];
        offs[i] = run;
        cursor[i] = run;
        dis[i] = rsqrtf(fmaxf((float)(c + 1), 1.0f));
        run += c;
    }
    if (t == 1023) offs[n] = ssum[1023];
}

__global__ void k_fill(const int* __restrict__ ei, int* __restrict__ cursor,
                       int* __restrict__ csr_row, int E, int n, const int* __restrict__ flags) {
    int e = blockIdx.x * blockDim.x + threadIdx.x;
    if (e >= E) return;
    bool i64 = flags[0] != 0;
    int r = ei[i64 ? 2LL * e : (long long)e];
    int c = ei[i64 ? 2LL * ((long long)E + e) : (long long)E + e];
    r = clampi(r, 0, n - 1);
    c = clampi(c, 0, n - 1);
    int pos = atomicAdd(&cursor[c], 1);
    if (pos >= 0 && pos < E) csr_row[pos] = r;
}

// ---- aggregation: dst[i,f] = act( dis[i]*( s(i,f) + sum_{r->i} s(r,f) ) + bias[f] )
template <int F, int SRCM, int DSTM, bool PRESCALED, bool RELU, bool HAS_BIAS>
__global__ void k_agg(const void* __restrict__ src, void* __restrict__ dst,
                      const int* __restrict__ offs, const int* __restrict__ csr_row,
                      const float* __restrict__ dis, const void* __restrict__ bias,
                      int n, int E, const int* __restrict__ flags) {
    int idx = blockIdx.x * blockDim.x + threadIdx.x;
    if (idx >= n * F) return;
    int fbf = flags[1];
    int i = idx / F;
    int f = idx - i * F;
    float di = dis[i];
    float self = ld_m<SRCM>(src, (long long)i * F + f, fbf);
    float acc = PRESCALED ? self : self * di;
    int e0 = offs[i], e1 = offs[i + 1];
    e0 = clampi(e0, 0, E);
    e1 = clampi(e1, e0, E);
    for (int e = e0; e < e1; ++e) {
        int r = clampi(csr_row[e], 0, n - 1);
        float v = ld_m<SRCM>(src, (long long)r * F + f, fbf);
        acc += PRESCALED ? v : v * dis[r];
    }
    float out = di * acc;
    if (HAS_BIAS) out += ld_m<2>(bias, f, fbf);
    if (RELU) out = relu_keepnan(out);
    st_m<DSTM>(dst, (long long)idx, out, fbf);
}

// ---- tiled SGEMM, f32 accumulate. C = act( (A@B) * (SCALE_ROW?dis[m]:1) + bias[n] )
// B and bias are input-dtype (dynamic); A/C modes templated.
template <int AM, int CM, bool SCALE_ROW, bool HAS_BIAS, bool RELU>
__global__ __launch_bounds__(256) void k_gemm(const void* __restrict__ A, const void* __restrict__ B,
                                              const void* __restrict__ bias, const float* __restrict__ dis,
                                              void* __restrict__ C, int M, int N, int K,
                                              const int* __restrict__ flags) {
    constexpr int BM = 128, BN = 64, BK = 16, TM = 8, TN = 4;
    __shared__ float As[BK][BM + 4];
    __shared__ float Bs[BK][BN + 4];
    const int fbf = flags[1];
    const int t = threadIdx.x;
    const int tx = t & 15;
    const int ty = t >> 4;
    const int bm = blockIdx.y * BM;
    const int bn = blockIdx.x * BN;
    float acc[TM][TN] = {};
    const int ar = t >> 1;
    const int ak = (t & 1) * 8;
    const int bnn = t & 63;
    const int bk0 = t >> 6;
    for (int k0 = 0; k0 < K; k0 += BK) {
        const int garow = bm + ar;
        #pragma unroll
        for (int j = 0; j < 8; j++) {
            int gk = k0 + ak + j;
            float v = (garow < M && gk < K) ? ld_m<AM>(A, (long long)garow * K + gk, fbf) : 0.f;
            As[ak + j][ar] = v;
        }
        const int gbn = bn + bnn;
        #pragma unroll
        for (int j = 0; j < 4; j++) {
            int gk = k0 + bk0 + j * 4;
            float v = (gbn < N && gk < K) ? ld_m<2>(B, (long long)gk * N + gbn, fbf) : 0.f;
            Bs[bk0 + j * 4][bnn] = v;
        }
        __syncthreads();
        #pragma unroll
        for (int kk = 0; kk < BK; kk++) {
            float a[TM], b[TN];
            #pragma unroll
            for (int i = 0; i < TM; i++) a[i] = As[kk][ty * TM + i];
            #pragma unroll
            for (int j = 0; j < TN; j++) b[j] = Bs[kk][tx * TN + j];
            #pragma unroll
            for (int i = 0; i < TM; i++)
                #pragma unroll
                for (int j = 0; j < TN; j++)
                    acc[i][j] = fmaf(a[i], b[j], acc[i][j]);
        }
        __syncthreads();
    }
    #pragma unroll
    for (int i = 0; i < TM; i++) {
        int gm = bm + ty * TM + i;
        if (gm >= M) continue;
        float sc = SCALE_ROW ? dis[gm] : 1.f;
        #pragma unroll
        for (int j = 0; j < TN; j++) {
            int gn = bn + tx * TN + j;
            if (gn >= N) continue;
            float v = acc[i][j] * sc;
            if (HAS_BIAS) v += ld_m<2>(bias, gn, fbf);
            if (RELU) v = relu_keepnan(v);
            st_m<CM>(C, (long long)gm * N + gn, v, fbf);
        }
    }
}

// layer-3 GEMV: t3[i] = dis[i] * dot(h2[i,:], W3)   (h2 bf16 fixed, W3 dynamic)
__global__ void k_gemv_w3(const bf16* __restrict__ X, const void* __restrict__ W3,
                          const float* __restrict__ dis, float* __restrict__ t3, int n, int K,
                          const int* __restrict__ flags) {
    int gt = blockIdx.x * blockDim.x + threadIdx.x;
    int w = gt >> 6, lane = gt & 63;
    if (w >= n) return;
    int fbf = flags[1];
    float s = 0.f;
    for (int k = lane; k < K; k += 64)
        s += __bfloat162float(X[(long long)w * K + k]) * ld_m<2>(W3, k, fbf);
    #pragma unroll
    for (int o = 32; o; o >>= 1) s += __shfl_down(s, o, 64);
    if (lane == 0) t3[w] = dis[w] * s;
}

extern "C" void kernel_launch(void* const* d_in, const int* in_sizes, int n_in,
                              void* d_out, int out_size, void* d_ws, size_t ws_size,
                              hipStream_t stream) {
    const void* x  = d_in[0];
    const int*  ei = (const int*)d_in[1];
    const void* W1 = d_in[2];
    const void* b1 = d_in[3];
    const void* W2 = d_in[4];
    const void* b2 = d_in[5];
    const void* W3 = d_in[6];
    const void* b3 = d_in[7];

    const int F0 = 58, F1 = 300, F2 = 100;
    const int N = in_sizes[0] / F0;
    const int E = in_sizes[1] / 2;

    // ---- workspace carve-up (~89 MB peak) ----
    size_t off = 0;
    auto alloc = [&](size_t bytes) -> void* {
        void* p = (char*)d_ws + off;
        off = (off + bytes + 255) & ~(size_t)255;
        return p;
    };
    int*   flags   = (int*)alloc(256);
    int*   cnt     = (int*)alloc((size_t)N * 4);
    int*   offs    = (int*)alloc((size_t)(N + 1) * 4);
    int*   cursor  = (int*)alloc((size_t)N * 4);
    float* dis     = (float*)alloc((size_t)N * 4);
    int*   csr_row = (int*)alloc((size_t)E * 4);
    // region A: z (N*58 f32, 23.2MB) -> t2 (N*100 bf16, 20MB) -> t3 (N f32): disjoint lifetimes
    void*  regA    = alloc((size_t)N * F0 * 4);
    float* z  = (float*)regA;
    bf16*  t2 = (bf16*)regA;
    float* t3 = (float*)regA;
    // region B: h1 (N*300 bf16, 60MB) -> h2 (N*100 bf16): h1 dead after GEMM2
    bf16*  regB    = (bf16*)alloc((size_t)N * F1 * 2);
    bf16*  h1 = regB;
    bf16*  h2 = regB;

    // ---- CSR build + dis + dtype detection ----
    k_init<<<1024, 256, 0, stream>>>(cnt, N, csr_row, E, ei, (const unsigned*)x, flags);
    k_count<<<(E + 255) / 256, 256, 0, stream>>>(ei, cnt, E, N, flags);
    k_scan_dis<<<1, 1024, 0, stream>>>(cnt, offs, cursor, dis, N);
    k_fill<<<(E + 255) / 256, 256, 0, stream>>>(ei, cursor, csr_row, E, N, flags);

    // ---- layer 1: aggregate at width 58 (src = input x, dst = f32 z), then GEMM ----
    k_agg<58, 2, 0, false, false, false><<<(N * F0 + 255) / 256, 256, 0, stream>>>(
        x, z, offs, csr_row, dis, nullptr, N, E, flags);
    k_gemm<0, 1, false, true, true><<<dim3((F1 + 63) / 64, (N + 127) / 128), 256, 0, stream>>>(
        z, W1, b1, dis, h1, N, F1, F0, flags);

    // ---- layer 2: GEMM (row-prescaled), then aggregate ----
    k_gemm<1, 1, true, false, false><<<dim3((F2 + 63) / 64, (N + 127) / 128), 256, 0, stream>>>(
        h1, W2, nullptr, dis, t2, N, F2, F1, flags);
    k_agg<100, 1, 1, true, true, true><<<(N * F2 + 255) / 256, 256, 0, stream>>>(
        t2, h2, offs, csr_row, dis, b2, N, E, flags);

    // ---- layer 3: GEMV (row-prescaled), then aggregate into output (dynamic dtype) ----
    k_gemv_w3<<<((long long)N * 64 + 255) / 256, 256, 0, stream>>>(h2, W3, dis, t3, N, F2, flags);
    k_agg<1, 0, 2, true, false, true><<<(N + 255) / 256, 256, 0, stream>>>(
        t3, d_out, offs, csr_row, dis, b3, N, E, flags);
}

// Round 5
// 763.043 us; speedup vs baseline: 1.4845x; 1.4845x over previous
//
#include <hip/hip_runtime.h>
#include <hip/hip_bf16.h>

typedef __hip_bfloat16 bf16;

// MODE: 0 = f32 fixed, 1 = bf16 fixed, 2 = dynamic (per flags[1])
template <int MODE>
__device__ __forceinline__ float ld_m(const void* p, long long i, int dynbf) {
    if (MODE == 0) return ((const float*)p)[i];
    if (MODE == 1) return __bfloat162float(((const bf16*)p)[i]);
    return dynbf ? __bfloat162float(((const bf16*)p)[i]) : ((const float*)p)[i];
}
template <int MODE>
__device__ __forceinline__ void st_m(void* p, long long i, float v, int dynbf) {
    if (MODE == 0) { ((float*)p)[i] = v; return; }
    if (MODE == 1) { ((bf16*)p)[i] = __float2bfloat16(v); return; }
    if (dynbf) ((bf16*)p)[i] = __float2bfloat16(v);
    else       ((float*)p)[i] = v;
}
// paired (2-feature) load/store; pi is the PAIR index
template <int MODE>
__device__ __forceinline__ float2 ld2_m(const void* p, long long pi, int dynbf) {
    bool bf = (MODE == 1) || (MODE == 2 && dynbf);
    if (bf) {
        unsigned w = ((const unsigned*)p)[pi];
        return make_float2(__uint_as_float(w << 16), __uint_as_float(w & 0xffff0000u));
    }
    return ((const float2*)p)[pi];
}
template <int MODE>
__device__ __forceinline__ void st2_m(void* p, long long pi, float vx, float vy, int dynbf) {
    bool bf = (MODE == 1) || (MODE == 2 && dynbf);
    if (bf) {
        bf16 a = __float2bfloat16(vx), b = __float2bfloat16(vy);
        unsigned wa = *(const unsigned short*)&a;
        unsigned wb = *(const unsigned short*)&b;
        ((unsigned*)p)[pi] = wa | (wb << 16);
    } else {
        ((float2*)p)[pi] = make_float2(vx, vy);
    }
}

__device__ __forceinline__ float relu_keepnan(float v) { return (v <= 0.f) ? 0.f : v; }
__device__ __forceinline__ int clampi(int v, int lo, int hi) {
    return v < lo ? lo : (v > hi ? hi : v);
}

// ---- init: zero cnt/csr_row; detect edge int64 (flags[0]) and float bf16 (flags[1]) ----
__global__ void k_init(int* __restrict__ cnt, int n, int* __restrict__ csr_row, int E,
                       const int* __restrict__ ei, const unsigned* __restrict__ xw,
                       int* __restrict__ flags) {
    int i = blockIdx.x * blockDim.x + threadIdx.x;
    int stride = gridDim.x * blockDim.x;
    for (int j = i; j < n; j += stride) cnt[j] = 0;
    for (int j = i; j < E; j += stride) csr_row[j] = 0;
    if (blockIdx.x == 0 && threadIdx.x < 64) {
        int lane = threadIdx.x;
        int ov = (lane < 16) ? ei[2 * lane + 1] : 0;
        unsigned long long be = __ballot(ov != 0);
        int inb = 0;
        #pragma unroll
        for (int q = 0; q < 2; ++q) {
            unsigned w = xw[lane + 64 * q];
            int e = (w >> 7) & 0xFF;
            inb += (e >= 110 && e <= 131) ? 1 : 0;
        }
        #pragma unroll
        for (int o = 32; o; o >>= 1) inb += __shfl_down(inb, o, 64);
        if (lane == 0) {
            flags[0] = (be == 0ULL) ? 1 : 0;   // edges are int64
            flags[1] = (inb >= 64) ? 1 : 0;    // floats are bf16
        }
    }
}

__global__ void k_count(const int* __restrict__ ei, int* __restrict__ cnt,
                        int E, int n, const int* __restrict__ flags) {
    int e = blockIdx.x * blockDim.x + threadIdx.x;
    if (e >= E) return;
    bool i64 = flags[0] != 0;
    int c = ei[i64 ? 2LL * ((long long)E + e) : (long long)E + e];
    c = clampi(c, 0, n - 1);
    atomicAdd(&cnt[c], 1);
}

// ---- parallel scan: phase 1, per-block (2048-elem) sums ----
__global__ void k_scan_partial(const int* __restrict__ cnt, int* __restrict__ bsum, int n) {
    __shared__ int sdata[256];
    int t = threadIdx.x;
    int base = blockIdx.x * 2048 + t * 8;
    int s = 0;
    #pragma unroll
    for (int j = 0; j < 8; j++) { int idx = base + j; if (idx < n) s += cnt[idx]; }
    sdata[t] = s;
    __syncthreads();
    for (int o = 128; o > 0; o >>= 1) {
        if (t < o) sdata[t] += sdata[t + o];
        __syncthreads();
    }
    if (t == 0) bsum[blockIdx.x] = sdata[0];
}

// ---- phase 2: prefix of bsums (in-block reduce) + local scan + offs/cursor/dis ----
__global__ void k_scan_final(const int* __restrict__ cnt, const int* __restrict__ bsum,
                             int* __restrict__ offs, int* __restrict__ cursor,
                             float* __restrict__ dis, int n) {
    __shared__ int ssc[256];
    __shared__ int sbase;
    int t = threadIdx.x;
    int blk = blockIdx.x;
    // exclusive prefix of block sums for this block
    int p = 0;
    for (int j = t; j < blk; j += 256) p += bsum[j];
    ssc[t] = p;
    __syncthreads();
    for (int o = 128; o > 0; o >>= 1) {
        if (t < o) ssc[t] += ssc[t + o];
        __syncthreads();
    }
    if (t == 0) sbase = ssc[0];
    __syncthreads();
    // local 2048-elem scan
    int base = blk * 2048 + t * 8;
    int val[8], loc[8];
    int s = 0;
    #pragma unroll
    for (int j = 0; j < 8; j++) {
        int idx = base + j;
        val[j] = (idx < n) ? cnt[idx] : 0;
        loc[j] = s;
        s += val[j];
    }
    ssc[t] = s;
    __syncthreads();
    for (int o = 1; o < 256; o <<= 1) {
        int v = (t >= o) ? ssc[t - o] : 0;
        __syncthreads();
        ssc[t] += v;
        __syncthreads();
    }
    int excl = (t > 0) ? ssc[t - 1] : 0;
    int b0 = sbase + excl;
    #pragma unroll
    for (int j = 0; j < 8; j++) {
        int idx = base + j;
        if (idx < n) {
            int o = b0 + loc[j];
            offs[idx] = o;
            cursor[idx] = o;
            dis[idx] = rsqrtf(fmaxf((float)(val[j] + 1), 1.0f));
        }
    }
    if (blk == gridDim.x - 1 && t == 255) offs[n] = sbase + ssc[255];
}

__global__ void k_fill(const int* __restrict__ ei, int* __restrict__ cursor,
                       int* __restrict__ csr_row, int E, int n, const int* __restrict__ flags) {
    int e = blockIdx.x * blockDim.x + threadIdx.x;
    if (e >= E) return;
    bool i64 = flags[0] != 0;
    int r = ei[i64 ? 2LL * e : (long long)e];
    int c = ei[i64 ? 2LL * ((long long)E + e) : (long long)E + e];
    r = clampi(r, 0, n - 1);
    c = clampi(c, 0, n - 1);
    int pos = atomicAdd(&cursor[c], 1);
    if (pos >= 0 && pos < E) csr_row[pos] = r;
}

// ---- scalar aggregation (F=1 path) ----
template <int F, int SRCM, int DSTM, bool PRESCALED, bool RELU, bool HAS_BIAS>
__global__ void k_agg(const void* __restrict__ src, void* __restrict__ dst,
                      const int* __restrict__ offs, const int* __restrict__ csr_row,
                      const float* __restrict__ dis, const void* __restrict__ bias,
                      int n, int E, const int* __restrict__ flags) {
    int idx = blockIdx.x * blockDim.x + threadIdx.x;
    if (idx >= n * F) return;
    int fbf = flags[1];
    int i = idx / F;
    int f = idx - i * F;
    float di = dis[i];
    float self = ld_m<SRCM>(src, (long long)i * F + f, fbf);
    float acc = PRESCALED ? self : self * di;
    int e0 = offs[i], e1 = offs[i + 1];
    e0 = clampi(e0, 0, E);
    e1 = clampi(e1, e0, E);
    for (int e = e0; e < e1; ++e) {
        int r = clampi(csr_row[e], 0, n - 1);
        float v = ld_m<SRCM>(src, (long long)r * F + f, fbf);
        acc += PRESCALED ? v : v * dis[r];
    }
    float out = di * acc;
    if (HAS_BIAS) out += ld_m<2>(bias, f, fbf);
    if (RELU) out = relu_keepnan(out);
    st_m<DSTM>(dst, (long long)idx, out, fbf);
}

// ---- paired aggregation (even F): thread handles features {2f, 2f+1} ----
template <int F, int SRCM, int DSTM, bool PRESCALED, bool RELU, bool HAS_BIAS>
__global__ void k_agg2(const void* __restrict__ src, void* __restrict__ dst,
                       const int* __restrict__ offs, const int* __restrict__ csr_row,
                       const float* __restrict__ dis, const void* __restrict__ bias,
                       int n, int E, const int* __restrict__ flags) {
    constexpr int H = F / 2;
    int idx = blockIdx.x * blockDim.x + threadIdx.x;
    if (idx >= n * H) return;
    int fbf = flags[1];
    int i = idx / H;
    int f2 = idx - i * H;
    float di = dis[i];
    float2 self = ld2_m<SRCM>(src, (long long)i * H + f2, fbf);
    float ax = PRESCALED ? self.x : self.x * di;
    float ay = PRESCALED ? self.y : self.y * di;
    int e0 = offs[i], e1 = offs[i + 1];
    e0 = clampi(e0, 0, E);
    e1 = clampi(e1, e0, E);
    for (int e = e0; e < e1; ++e) {
        int r = clampi(csr_row[e], 0, n - 1);
        float2 v = ld2_m<SRCM>(src, (long long)r * H + f2, fbf);
        if (PRESCALED) { ax += v.x; ay += v.y; }
        else { float w = dis[r]; ax = fmaf(v.x, w, ax); ay = fmaf(v.y, w, ay); }
    }
    float ox = di * ax, oy = di * ay;
    if (HAS_BIAS) {
        float2 b = ld2_m<2>(bias, f2, fbf);
        ox += b.x; oy += b.y;
    }
    if (RELU) { ox = relu_keepnan(ox); oy = relu_keepnan(oy); }
    st2_m<DSTM>(dst, (long long)idx, ox, oy, fbf);
}

// ---- tiled SGEMM, f32 accumulate. C = act( (A@B) * (SCALE_ROW?dis[m]:1) + bias[n] )
template <int AM, int CM, bool SCALE_ROW, bool HAS_BIAS, bool RELU>
__global__ __launch_bounds__(256) void k_gemm(const void* __restrict__ A, const void* __restrict__ B,
                                              const void* __restrict__ bias, const float* __restrict__ dis,
                                              void* __restrict__ C, int M, int N, int K,
                                              const int* __restrict__ flags) {
    constexpr int BM = 128, BN = 64, BK = 16, TM = 8, TN = 4;
    __shared__ float As[BK][BM + 4];
    __shared__ float Bs[BK][BN + 4];
    const int fbf = flags[1];
    const int t = threadIdx.x;
    const int tx = t & 15;
    const int ty = t >> 4;
    const int bm = blockIdx.y * BM;
    const int bn = blockIdx.x * BN;
    float acc[TM][TN] = {};
    const int ar = t >> 1;
    const int ak = (t & 1) * 8;
    const int bnn = t & 63;
    const int bk0 = t >> 6;
    for (int k0 = 0; k0 < K; k0 += BK) {
        const int garow = bm + ar;
        #pragma unroll
        for (int j = 0; j < 8; j++) {
            int gk = k0 + ak + j;
            float v = (garow < M && gk < K) ? ld_m<AM>(A, (long long)garow * K + gk, fbf) : 0.f;
            As[ak + j][ar] = v;
        }
        const int gbn = bn + bnn;
        #pragma unroll
        for (int j = 0; j < 4; j++) {
            int gk = k0 + bk0 + j * 4;
            float v = (gbn < N && gk < K) ? ld_m<2>(B, (long long)gk * N + gbn, fbf) : 0.f;
            Bs[bk0 + j * 4][bnn] = v;
        }
        __syncthreads();
        #pragma unroll
        for (int kk = 0; kk < BK; kk++) {
            float a[TM], b[TN];
            #pragma unroll
            for (int i = 0; i < TM; i++) a[i] = As[kk][ty * TM + i];
            #pragma unroll
            for (int j = 0; j < TN; j++) b[j] = Bs[kk][tx * TN + j];
            #pragma unroll
            for (int i = 0; i < TM; i++)
                #pragma unroll
                for (int j = 0; j < TN; j++)
                    acc[i][j] = fmaf(a[i], b[j], acc[i][j]);
        }
        __syncthreads();
    }
    #pragma unroll
    for (int i = 0; i < TM; i++) {
        int gm = bm + ty * TM + i;
        if (gm >= M) continue;
        float sc = SCALE_ROW ? dis[gm] : 1.f;
        #pragma unroll
        for (int j = 0; j < TN; j++) {
            int gn = bn + tx * TN + j;
            if (gn >= N) continue;
            float v = acc[i][j] * sc;
            if (HAS_BIAS) v += ld_m<2>(bias, gn, fbf);
            if (RELU) v = relu_keepnan(v);
            st_m<CM>(C, (long long)gm * N + gn, v, fbf);
        }
    }
}

// layer-3 GEMV: t3[i] = dis[i] * dot(h2[i,:], W3)
__global__ void k_gemv_w3(const bf16* __restrict__ X, const void* __restrict__ W3,
                          const float* __restrict__ dis, float* __restrict__ t3, int n, int K,
                          const int* __restrict__ flags) {
    int gt = blockIdx.x * blockDim.x + threadIdx.x;
    int w = gt >> 6, lane = gt & 63;
    if (w >= n) return;
    int fbf = flags[1];
    float s = 0.f;
    for (int k = lane; k < K; k += 64)
        s += __bfloat162float(X[(long long)w * K + k]) * ld_m<2>(W3, k, fbf);
    #pragma unroll
    for (int o = 32; o; o >>= 1) s += __shfl_down(s, o, 64);
    if (lane == 0) t3[w] = dis[w] * s;
}

extern "C" void kernel_launch(void* const* d_in, const int* in_sizes, int n_in,
                              void* d_out, int out_size, void* d_ws, size_t ws_size,
                              hipStream_t stream) {
    const void* x  = d_in[0];
    const int*  ei = (const int*)d_in[1];
    const void* W1 = d_in[2];
    const void* b1 = d_in[3];
    const void* W2 = d_in[4];
    const void* b2 = d_in[5];
    const void* W3 = d_in[6];
    const void* b3 = d_in[7];

    const int F0 = 58, F1 = 300, F2 = 100;
    const int N = in_sizes[0] / F0;
    const int E = in_sizes[1] / 2;
    const int nb = (N + 2047) / 2048;

    size_t off = 0;
    auto alloc = [&](size_t bytes) -> void* {
        void* p = (char*)d_ws + off;
        off = (off + bytes + 255) & ~(size_t)255;
        return p;
    };
    int*   flags   = (int*)alloc(256);
    int*   cnt     = (int*)alloc((size_t)N * 4);
    int*   offs    = (int*)alloc((size_t)(N + 1) * 4);
    int*   cursor  = (int*)alloc((size_t)N * 4);
    float* dis     = (float*)alloc((size_t)N * 4);
    int*   bsum    = (int*)alloc((size_t)nb * 4);
    int*   csr_row = (int*)alloc((size_t)E * 4);
    // region A: z (N*58 f32) -> t2 (N*100 bf16) -> t3 (N f32): disjoint lifetimes
    void*  regA    = alloc((size_t)N * F0 * 4);
    float* z  = (float*)regA;
    bf16*  t2 = (bf16*)regA;
    float* t3 = (float*)regA;
    // region B: h1 (N*300 bf16) -> h2 (N*100 bf16)
    bf16*  regB    = (bf16*)alloc((size_t)N * F1 * 2);
    bf16*  h1 = regB;
    bf16*  h2 = regB;

    // ---- CSR build + dis + dtype detection ----
    k_init<<<1024, 256, 0, stream>>>(cnt, N, csr_row, E, ei, (const unsigned*)x, flags);
    k_count<<<(E + 255) / 256, 256, 0, stream>>>(ei, cnt, E, N, flags);
    k_scan_partial<<<nb, 256, 0, stream>>>(cnt, bsum, N);
    k_scan_final<<<nb, 256, 0, stream>>>(cnt, bsum, offs, cursor, dis, N);
    k_fill<<<(E + 255) / 256, 256, 0, stream>>>(ei, cursor, csr_row, E, N, flags);

    // ---- layer 1: aggregate at width 58 (paired), then GEMM ----
    k_agg2<58, 2, 0, false, false, false><<<((long long)N * 29 + 255) / 256, 256, 0, stream>>>(
        x, z, offs, csr_row, dis, nullptr, N, E, flags);
    k_gemm<0, 1, false, true, true><<<dim3((F1 + 63) / 64, (N + 127) / 128), 256, 0, stream>>>(
        z, W1, b1, dis, h1, N, F1, F0, flags);

    // ---- layer 2: GEMM (row-prescaled), then aggregate (paired) ----
    k_gemm<1, 1, true, false, false><<<dim3((F2 + 63) / 64, (N + 127) / 128), 256, 0, stream>>>(
        h1, W2, nullptr, dis, t2, N, F2, F1, flags);
    k_agg2<100, 1, 1, true, true, true><<<((long long)N * 50 + 255) / 256, 256, 0, stream>>>(
        t2, h2, offs, csr_row, dis, b2, N, E, flags);

    // ---- layer 3: GEMV (row-prescaled), then aggregate into output ----
    k_gemv_w3<<<((long long)N * 64 + 255) / 256, 256, 0, stream>>>(h2, W3, dis, t3, N, F2, flags);
    k_agg<1, 0, 2, true, false, true><<<(N + 255) / 256, 256, 0, stream>>>(
        t3, d_out, offs, csr_row, dis, b3, N, E, flags);
}

// Round 6
// 492.889 us; speedup vs baseline: 2.2982x; 1.5481x over previous
//
#include <hip/hip_runtime.h>
#include <hip/hip_bf16.h>

typedef __hip_bfloat16 bf16;
typedef __attribute__((ext_vector_type(8))) short s8v;   // 8 bf16 = 4 VGPRs (MFMA A/B frag)
typedef __attribute__((ext_vector_type(4))) float f4v;   // 4 f32 (MFMA C/D frag)

// MODE: 0 = f32 fixed, 1 = bf16 fixed, 2 = dynamic (per flags[1])
template <int MODE>
__device__ __forceinline__ float ld_m(const void* p, long long i, int dynbf) {
    if (MODE == 0) return ((const float*)p)[i];
    if (MODE == 1) return __bfloat162float(((const bf16*)p)[i]);
    return dynbf ? __bfloat162float(((const bf16*)p)[i]) : ((const float*)p)[i];
}
template <int MODE>
__device__ __forceinline__ void st_m(void* p, long long i, float v, int dynbf) {
    if (MODE == 0) { ((float*)p)[i] = v; return; }
    if (MODE == 1) { ((bf16*)p)[i] = __float2bfloat16(v); return; }
    if (dynbf) ((bf16*)p)[i] = __float2bfloat16(v);
    else       ((float*)p)[i] = v;
}
// paired (2-feature) load/store; pi is the PAIR index
template <int MODE>
__device__ __forceinline__ float2 ld2_m(const void* p, long long pi, int dynbf) {
    bool bf = (MODE == 1) || (MODE == 2 && dynbf);
    if (bf) {
        unsigned w = ((const unsigned*)p)[pi];
        return make_float2(__uint_as_float(w << 16), __uint_as_float(w & 0xffff0000u));
    }
    return ((const float2*)p)[pi];
}
template <int MODE>
__device__ __forceinline__ void st2_m(void* p, long long pi, float vx, float vy, int dynbf) {
    bool bf = (MODE == 1) || (MODE == 2 && dynbf);
    if (bf) {
        bf16 a = __float2bfloat16(vx), b = __float2bfloat16(vy);
        unsigned wa = *(const unsigned short*)&a;
        unsigned wb = *(const unsigned short*)&b;
        ((unsigned*)p)[pi] = wa | (wb << 16);
    } else {
        ((float2*)p)[pi] = make_float2(vx, vy);
    }
}

__device__ __forceinline__ float relu_keepnan(float v) { return (v <= 0.f) ? 0.f : v; }
__device__ __forceinline__ int clampi(int v, int lo, int hi) {
    return v < lo ? lo : (v > hi ? hi : v);
}
__device__ __forceinline__ short f2bf_bits(float v) {
    bf16 h = __float2bfloat16(v);
    return *(short*)&h;
}

// ---- init: zero cnt/csr_row; detect edge int64 (flags[0]) and float bf16 (flags[1]) ----
__global__ void k_init(int* __restrict__ cnt, int n, int* __restrict__ csr_row, int E,
                       const int* __restrict__ ei, const unsigned* __restrict__ xw,
                       int* __restrict__ flags) {
    int i = blockIdx.x * blockDim.x + threadIdx.x;
    int stride = gridDim.x * blockDim.x;
    for (int j = i; j < n; j += stride) cnt[j] = 0;
    for (int j = i; j < E; j += stride) csr_row[j] = 0;
    if (blockIdx.x == 0 && threadIdx.x < 64) {
        int lane = threadIdx.x;
        int ov = (lane < 16) ? ei[2 * lane + 1] : 0;
        unsigned long long be = __ballot(ov != 0);
        int inb = 0;
        #pragma unroll
        for (int q = 0; q < 2; ++q) {
            unsigned w = xw[lane + 64 * q];
            int e = (w >> 7) & 0xFF;
            inb += (e >= 110 && e <= 131) ? 1 : 0;
        }
        #pragma unroll
        for (int o = 32; o; o >>= 1) inb += __shfl_down(inb, o, 64);
        if (lane == 0) {
            flags[0] = (be == 0ULL) ? 1 : 0;   // edges are int64
            flags[1] = (inb >= 64) ? 1 : 0;    // floats are bf16
        }
    }
}

__global__ void k_count(const int* __restrict__ ei, int* __restrict__ cnt,
                        int E, int n, const int* __restrict__ flags) {
    int e = blockIdx.x * blockDim.x + threadIdx.x;
    if (e >= E) return;
    bool i64 = flags[0] != 0;
    int c = ei[i64 ? 2LL * ((long long)E + e) : (long long)E + e];
    c = clampi(c, 0, n - 1);
    atomicAdd(&cnt[c], 1);
}

// ---- parallel scan: phase 1, per-block (2048-elem) sums ----
__global__ void k_scan_partial(const int* __restrict__ cnt, int* __restrict__ bsum, int n) {
    __shared__ int sdata[256];
    int t = threadIdx.x;
    int base = blockIdx.x * 2048 + t * 8;
    int s = 0;
    #pragma unroll
    for (int j = 0; j < 8; j++) { int idx = base + j; if (idx < n) s += cnt[idx]; }
    sdata[t] = s;
    __syncthreads();
    for (int o = 128; o > 0; o >>= 1) {
        if (t < o) sdata[t] += sdata[t + o];
        __syncthreads();
    }
    if (t == 0) bsum[blockIdx.x] = sdata[0];
}

// ---- phase 2: prefix of bsums + local scan + offs/cursor/dis ----
__global__ void k_scan_final(const int* __restrict__ cnt, const int* __restrict__ bsum,
                             int* __restrict__ offs, int* __restrict__ cursor,
                             float* __restrict__ dis, int n) {
    __shared__ int ssc[256];
    __shared__ int sbase;
    int t = threadIdx.x;
    int blk = blockIdx.x;
    int p = 0;
    for (int j = t; j < blk; j += 256) p += bsum[j];
    ssc[t] = p;
    __syncthreads();
    for (int o = 128; o > 0; o >>= 1) {
        if (t < o) ssc[t] += ssc[t + o];
        __syncthreads();
    }
    if (t == 0) sbase = ssc[0];
    __syncthreads();
    int base = blk * 2048 + t * 8;
    int val[8], loc[8];
    int s = 0;
    #pragma unroll
    for (int j = 0; j < 8; j++) {
        int idx = base + j;
        val[j] = (idx < n) ? cnt[idx] : 0;
        loc[j] = s;
        s += val[j];
    }
    ssc[t] = s;
    __syncthreads();
    for (int o = 1; o < 256; o <<= 1) {
        int v = (t >= o) ? ssc[t - o] : 0;
        __syncthreads();
        ssc[t] += v;
        __syncthreads();
    }
    int excl = (t > 0) ? ssc[t - 1] : 0;
    int b0 = sbase + excl;
    #pragma unroll
    for (int j = 0; j < 8; j++) {
        int idx = base + j;
        if (idx < n) {
            int o = b0 + loc[j];
            offs[idx] = o;
            cursor[idx] = o;
            dis[idx] = rsqrtf(fmaxf((float)(val[j] + 1), 1.0f));
        }
    }
    if (blk == gridDim.x - 1 && t == 255) offs[n] = sbase + ssc[255];
}

__global__ void k_fill(const int* __restrict__ ei, int* __restrict__ cursor,
                       int* __restrict__ csr_row, int E, int n, const int* __restrict__ flags) {
    int e = blockIdx.x * blockDim.x + threadIdx.x;
    if (e >= E) return;
    bool i64 = flags[0] != 0;
    int r = ei[i64 ? 2LL * e : (long long)e];
    int c = ei[i64 ? 2LL * ((long long)E + e) : (long long)E + e];
    r = clampi(r, 0, n - 1);
    c = clampi(c, 0, n - 1);
    int pos = atomicAdd(&cursor[c], 1);
    if (pos >= 0 && pos < E) csr_row[pos] = r;
}

// ---- weight prep: W1t[n][k] bf16 [320][64], W2t[n][k] bf16 [128][320], zero-padded ----
__global__ void k_wtrans(const void* __restrict__ W1, const void* __restrict__ W2,
                         short* __restrict__ W1t, short* __restrict__ W2t,
                         const int* __restrict__ flags) {
    int fbf = flags[1];
    int i = blockIdx.x * blockDim.x + threadIdx.x;
    if (i < 320 * 64) {
        int nn = i >> 6, k = i & 63;
        float v = (nn < 300 && k < 58) ? ld_m<2>(W1, (long long)k * 300 + nn, fbf) : 0.f;
        W1t[i] = f2bf_bits(v);
    }
    int j = i - 320 * 64;
    if (j >= 0 && j < 128 * 320) {
        int nn = j / 320, k = j - nn * 320;
        float v = (nn < 100 && k < 300) ? ld_m<2>(W2, (long long)k * 100 + nn, fbf) : 0.f;
        W2t[j] = f2bf_bits(v);
    }
}

// ---- scalar aggregation (F=1 path, final output) ----
template <int SRCM, int DSTM, bool PRESCALED, bool RELU, bool HAS_BIAS>
__global__ void k_agg1(const void* __restrict__ src, void* __restrict__ dst,
                       const int* __restrict__ offs, const int* __restrict__ csr_row,
                       const float* __restrict__ dis, const void* __restrict__ bias,
                       int n, int E, const int* __restrict__ flags) {
    int i = blockIdx.x * blockDim.x + threadIdx.x;
    if (i >= n) return;
    int fbf = flags[1];
    float di = dis[i];
    float self = ld_m<SRCM>(src, i, fbf);
    float acc = PRESCALED ? self : self * di;
    int e0 = offs[i], e1 = offs[i + 1];
    e0 = clampi(e0, 0, E);
    e1 = clampi(e1, e0, E);
    for (int e = e0; e < e1; ++e) {
        int r = clampi(csr_row[e], 0, n - 1);
        float v = ld_m<SRCM>(src, r, fbf);
        acc += PRESCALED ? v : v * dis[r];
    }
    float out = di * acc;
    if (HAS_BIAS) out += ld_m<2>(bias, 0, fbf);
    if (RELU) out = relu_keepnan(out);
    st_m<DSTM>(dst, i, out, fbf);
}

// ---- paired aggregation. DSP threads/node; pairs f2<HV aggregated, HV<=f2<DSP zero-fill.
// SS/DS = src/dst pair strides.
template <int DSP, int HV, int SS, int DS, int SRCM, int DSTM,
          bool PRESCALED, bool RELU, bool HAS_BIAS>
__global__ void k_agg2(const void* __restrict__ src, void* __restrict__ dst,
                       const int* __restrict__ offs, const int* __restrict__ csr_row,
                       const float* __restrict__ dis, const void* __restrict__ bias,
                       int n, int E, const int* __restrict__ flags) {
    long long idx = (long long)blockIdx.x * blockDim.x + threadIdx.x;
    if (idx >= (long long)n * DSP) return;
    int fbf = flags[1];
    int i = (int)(idx / DSP);
    int f2 = (int)(idx - (long long)i * DSP);
    if (f2 >= HV) { st2_m<DSTM>(dst, (long long)i * DS + f2, 0.f, 0.f, fbf); return; }
    float di = dis[i];
    float2 self = ld2_m<SRCM>(src, (long long)i * SS + f2, fbf);
    float ax = PRESCALED ? self.x : self.x * di;
    float ay = PRESCALED ? self.y : self.y * di;
    int e0 = offs[i], e1 = offs[i + 1];
    e0 = clampi(e0, 0, E);
    e1 = clampi(e1, e0, E);
    for (int e = e0; e < e1; ++e) {
        int r = clampi(csr_row[e], 0, n - 1);
        float2 v = ld2_m<SRCM>(src, (long long)r * SS + f2, fbf);
        if (PRESCALED) { ax += v.x; ay += v.y; }
        else { float w = dis[r]; ax = fmaf(v.x, w, ax); ay = fmaf(v.y, w, ay); }
    }
    float ox = di * ax, oy = di * ay;
    if (HAS_BIAS) {
        float2 b = ld2_m<2>(bias, f2, fbf);
        ox += b.x; oy += b.y;
    }
    if (RELU) { ox = relu_keepnan(ox); oy = relu_keepnan(oy); }
    st2_m<DSTM>(dst, (long long)i * DS + f2, ox, oy, fbf);
}

// ---- MFMA bf16 GEMM: C[M][ldc](bf16) = act( A[M][KP](bf16) @ Bt^T * scale + bias ) ----
// A row stride = KP (multiple of 32, zero-padded). Bt[n][k] bf16, row stride KP,
// zero-padded to gridDim.x*BN rows. BM=128, BN=NT*16; 4 waves, each 32 rows x BN cols.
// Verified layouts: A frag m=lane&15,k=quad*8+j; B frag n=lane&15,k=quad*8+j;
// C/D col=lane&15,row=quad*4+reg.
template <int NT, bool SCALE_ROW, bool HAS_BIAS, bool RELU>
__global__ __launch_bounds__(256) void k_gemm_mfma(
    const ushort* __restrict__ A, const ushort* __restrict__ Bt,
    const void* __restrict__ bias, const float* __restrict__ dis,
    bf16* __restrict__ C, int M, int KP, int chunks, int ldc, int NBreal,
    const int* __restrict__ flags) {
    constexpr int BN = NT * 16;
    __shared__ __align__(16) ushort A_s[128][40];   // stride 40: 2-way max bank aliasing
    __shared__ __align__(16) ushort B_s[BN][40];
    const int t = threadIdx.x;
    const int lane = t & 63;
    const int w = t >> 6;
    const int bm = blockIdx.y * 128;
    const int bn = blockIdx.x * BN;
    const int fbf = flags[1];
    const int mrow = lane & 15;
    const int quad = lane >> 4;

    f4v acc[2][NT];
    #pragma unroll
    for (int a = 0; a < 2; a++)
        #pragma unroll
        for (int b = 0; b < NT; b++)
            #pragma unroll
            for (int r = 0; r < 4; r++) acc[a][b][r] = 0.f;

    for (int c = 0; c < chunks; ++c) {
        const int k0 = c * 32;
        // stage A tile: 128 rows x 32 k (512 units of 16B)
        #pragma unroll
        for (int r = 0; r < 2; ++r) {
            int u = t + r * 256;
            int row = u >> 2, kq = (u & 3) * 8;
            int grow = bm + row;
            uint4 v = make_uint4(0u, 0u, 0u, 0u);
            if (grow < M) v = *(const uint4*)(A + (size_t)grow * KP + k0 + kq);
            *(uint4*)&A_s[row][kq] = v;
        }
        // stage B tile: BN rows x 32 k
        for (int u = t; u < BN * 4; u += 256) {
            int row = u >> 2, kq = (u & 3) * 8;
            uint4 v = *(const uint4*)(Bt + (size_t)(bn + row) * KP + k0 + kq);
            *(uint4*)&B_s[row][kq] = v;
        }
        __syncthreads();
        s8v a0 = *(const s8v*)&A_s[w * 32 + mrow][quad * 8];
        s8v a1 = *(const s8v*)&A_s[w * 32 + 16 + mrow][quad * 8];
        #pragma unroll
        for (int nt = 0; nt < NT; ++nt) {
            s8v b = *(const s8v*)&B_s[nt * 16 + mrow][quad * 8];
            acc[0][nt] = __builtin_amdgcn_mfma_f32_16x16x32_bf16(a0, b, acc[0][nt], 0, 0, 0);
            acc[1][nt] = __builtin_amdgcn_mfma_f32_16x16x32_bf16(a1, b, acc[1][nt], 0, 0, 0);
        }
        __syncthreads();
    }
    // epilogue
    float sc[2][4];
    #pragma unroll
    for (int mi = 0; mi < 2; ++mi)
        #pragma unroll
        for (int r = 0; r < 4; ++r) {
            int gm = bm + w * 32 + mi * 16 + quad * 4 + r;
            sc[mi][r] = (SCALE_ROW && gm < M) ? dis[gm] : 1.f;
        }
    #pragma unroll
    for (int nt = 0; nt < NT; ++nt) {
        int gn = bn + nt * 16 + mrow;
        float bv = 0.f;
        if (HAS_BIAS) bv = (gn < NBreal) ? ld_m<2>(bias, gn, fbf) : 0.f;
        #pragma unroll
        for (int mi = 0; mi < 2; ++mi)
            #pragma unroll
            for (int r = 0; r < 4; ++r) {
                int gm = bm + w * 32 + mi * 16 + quad * 4 + r;
                if (gm >= M) continue;
                float v = acc[mi][nt][r] * sc[mi][r];
                if (HAS_BIAS) v += bv;
                if (RELU) v = relu_keepnan(v);
                C[(size_t)gm * ldc + gn] = __float2bfloat16(v);
            }
    }
}

// layer-3 GEMV: t3[i] = dis[i] * dot(h2[i,:], W3)
__global__ void k_gemv_w3(const bf16* __restrict__ X, const void* __restrict__ W3,
                          const float* __restrict__ dis, float* __restrict__ t3, int n, int K,
                          const int* __restrict__ flags) {
    int gt = blockIdx.x * blockDim.x + threadIdx.x;
    int w = gt >> 6, lane = gt & 63;
    if (w >= n) return;
    int fbf = flags[1];
    float s = 0.f;
    for (int k = lane; k < K; k += 64)
        s += __bfloat162float(X[(long long)w * K + k]) * ld_m<2>(W3, k, fbf);
    #pragma unroll
    for (int o = 32; o; o >>= 1) s += __shfl_down(s, o, 64);
    if (lane == 0) t3[w] = dis[w] * s;
}

extern "C" void kernel_launch(void* const* d_in, const int* in_sizes, int n_in,
                              void* d_out, int out_size, void* d_ws, size_t ws_size,
                              hipStream_t stream) {
    const void* x  = d_in[0];
    const int*  ei = (const int*)d_in[1];
    const void* W1 = d_in[2];
    const void* b1 = d_in[3];
    const void* W2 = d_in[4];
    const void* b2 = d_in[5];
    const void* W3 = d_in[6];
    const void* b3 = d_in[7];

    const int F0 = 58, F1 = 300, F2 = 100;
    const int N = in_sizes[0] / F0;
    const int E = in_sizes[1] / 2;
    const int nb = (N + 2047) / 2048;
    const int gy = (N + 127) / 128;

    size_t off = 0;
    auto alloc = [&](size_t bytes) -> void* {
        void* p = (char*)d_ws + off;
        off = (off + bytes + 255) & ~(size_t)255;
        return p;
    };
    int*   flags   = (int*)alloc(256);
    int*   cnt     = (int*)alloc((size_t)N * 4);
    int*   offs    = (int*)alloc((size_t)(N + 1) * 4);
    int*   cursor  = (int*)alloc((size_t)N * 4);
    float* dis     = (float*)alloc((size_t)N * 4);
    int*   bsum    = (int*)alloc((size_t)nb * 4);
    int*   csr_row = (int*)alloc((size_t)E * 4);
    short* W1t     = (short*)alloc((size_t)320 * 64 * 2);
    short* W2t     = (short*)alloc((size_t)128 * 320 * 2);
    // region A: z_bf [N][64] bf16 (12.8MB) -> t2 [N][128] bf16 (25.6MB) -> t3 [N] f32
    void*  regA    = alloc((size_t)N * 128 * 2);
    ushort* z_bf = (ushort*)regA;
    bf16*   t2   = (bf16*)regA;
    float*  t3   = (float*)regA;
    // region B: h1 [N][320] bf16 (64MB) -> h2 [N][100] bf16 (20MB)
    void*  regB    = alloc((size_t)N * 320 * 2);
    bf16*  h1 = (bf16*)regB;
    bf16*  h2 = (bf16*)regB;

    // ---- CSR build + dis + dtype detection + weight prep ----
    k_init<<<1024, 256, 0, stream>>>(cnt, N, csr_row, E, ei, (const unsigned*)x, flags);
    k_count<<<(E + 255) / 256, 256, 0, stream>>>(ei, cnt, E, N, flags);
    k_scan_partial<<<nb, 256, 0, stream>>>(cnt, bsum, N);
    k_scan_final<<<nb, 256, 0, stream>>>(cnt, bsum, offs, cursor, dis, N);
    k_fill<<<(E + 255) / 256, 256, 0, stream>>>(ei, cursor, csr_row, E, N, flags);
    k_wtrans<<<(320 * 64 + 128 * 320 + 255) / 256, 256, 0, stream>>>(W1, W2, W1t, W2t, flags);

    // ---- layer 1: aggregate x at width 58 -> z_bf [N][64] (pad zeroed), then MFMA GEMM ----
    k_agg2<32, 29, 29, 32, 2, 1, false, false, false>
        <<<((long long)N * 32 + 255) / 256, 256, 0, stream>>>(
        x, z_bf, offs, csr_row, dis, nullptr, N, E, flags);
    k_gemm_mfma<4, false, true, true><<<dim3(5, gy), 256, 0, stream>>>(
        z_bf, (const ushort*)W1t, b1, dis, h1, N, 64, 2, 320, 300, flags);

    // ---- layer 2: MFMA GEMM (row-prescaled) -> t2 [N][128], then aggregate -> h2 [N][100] ----
    k_gemm_mfma<8, true, false, false><<<dim3(1, gy), 256, 0, stream>>>(
        (const ushort*)h1, (const ushort*)W2t, nullptr, dis, t2, N, 320, 10, 128, 0, flags);
    k_agg2<50, 50, 64, 50, 1, 1, true, true, true>
        <<<((long long)N * 50 + 255) / 256, 256, 0, stream>>>(
        t2, h2, offs, csr_row, dis, b2, N, E, flags);

    // ---- layer 3: GEMV (row-prescaled), then aggregate into output ----
    k_gemv_w3<<<((long long)N * 64 + 255) / 256, 256, 0, stream>>>(h2, W3, dis, t3, N, F2, flags);
    k_agg1<0, 2, true, false, true><<<(N + 255) / 256, 256, 0, stream>>>(
        t3, d_out, offs, csr_row, dis, b3, N, E, flags);
}

// Round 7
// 425.965 us; speedup vs baseline: 2.6592x; 1.1571x over previous
//
#include <hip/hip_runtime.h>
#include <hip/hip_bf16.h>

typedef __hip_bfloat16 bf16;
typedef __attribute__((ext_vector_type(8))) short s8v;   // 8 bf16 = 4 VGPRs (MFMA A/B frag)
typedef __attribute__((ext_vector_type(4))) float f4v;   // 4 f32 (MFMA C/D frag)

// MODE: 0 = f32 fixed, 1 = bf16 fixed, 2 = dynamic (per flags[1])
template <int MODE>
__device__ __forceinline__ float ld_m(const void* p, long long i, int dynbf) {
    if (MODE == 0) return ((const float*)p)[i];
    if (MODE == 1) return __bfloat162float(((const bf16*)p)[i]);
    return dynbf ? __bfloat162float(((const bf16*)p)[i]) : ((const float*)p)[i];
}
template <int MODE>
__device__ __forceinline__ void st_m(void* p, long long i, float v, int dynbf) {
    if (MODE == 0) { ((float*)p)[i] = v; return; }
    if (MODE == 1) { ((bf16*)p)[i] = __float2bfloat16(v); return; }
    if (dynbf) ((bf16*)p)[i] = __float2bfloat16(v);
    else       ((float*)p)[i] = v;
}
// paired (2-feature) load/store; pi is the PAIR index
template <int MODE>
__device__ __forceinline__ float2 ld2_m(const void* p, long long pi, int dynbf) {
    bool bf = (MODE == 1) || (MODE == 2 && dynbf);
    if (bf) {
        unsigned w = ((const unsigned*)p)[pi];
        return make_float2(__uint_as_float(w << 16), __uint_as_float(w & 0xffff0000u));
    }
    return ((const float2*)p)[pi];
}
template <int MODE>
__device__ __forceinline__ void st2_m(void* p, long long pi, float vx, float vy, int dynbf) {
    bool bf = (MODE == 1) || (MODE == 2 && dynbf);
    if (bf) {
        bf16 a = __float2bfloat16(vx), b = __float2bfloat16(vy);
        unsigned wa = *(const unsigned short*)&a;
        unsigned wb = *(const unsigned short*)&b;
        ((unsigned*)p)[pi] = wa | (wb << 16);
    } else {
        ((float2*)p)[pi] = make_float2(vx, vy);
    }
}

__device__ __forceinline__ float relu_keepnan(float v) { return (v <= 0.f) ? 0.f : v; }
__device__ __forceinline__ int clampi(int v, int lo, int hi) {
    return v < lo ? lo : (v > hi ? hi : v);
}
__device__ __forceinline__ short f2bf_bits(float v) {
    bf16 h = __float2bfloat16(v);
    return *(short*)&h;
}
__device__ __forceinline__ float bflo(unsigned w) { return __uint_as_float(w << 16); }
__device__ __forceinline__ float bfhi(unsigned w) { return __uint_as_float(w & 0xffff0000u); }

// ---- init: zero cnt/csr_row; detect edge int64 (flags[0]) and float bf16 (flags[1]) ----
__global__ void k_init(int* __restrict__ cnt, int n, int* __restrict__ csr_row, int E,
                       const int* __restrict__ ei, const unsigned* __restrict__ xw,
                       int* __restrict__ flags) {
    int i = blockIdx.x * blockDim.x + threadIdx.x;
    int stride = gridDim.x * blockDim.x;
    for (int j = i; j < n; j += stride) cnt[j] = 0;
    for (int j = i; j < E; j += stride) csr_row[j] = 0;
    if (blockIdx.x == 0 && threadIdx.x < 64) {
        int lane = threadIdx.x;
        int ov = (lane < 16) ? ei[2 * lane + 1] : 0;
        unsigned long long be = __ballot(ov != 0);
        int inb = 0;
        #pragma unroll
        for (int q = 0; q < 2; ++q) {
            unsigned w = xw[lane + 64 * q];
            int e = (w >> 7) & 0xFF;
            inb += (e >= 110 && e <= 131) ? 1 : 0;
        }
        #pragma unroll
        for (int o = 32; o; o >>= 1) inb += __shfl_down(inb, o, 64);
        if (lane == 0) {
            flags[0] = (be == 0ULL) ? 1 : 0;   // edges are int64
            flags[1] = (inb >= 64) ? 1 : 0;    // floats are bf16
        }
    }
}

__global__ void k_count(const int* __restrict__ ei, int* __restrict__ cnt,
                        int E, int n, const int* __restrict__ flags) {
    int e = blockIdx.x * blockDim.x + threadIdx.x;
    if (e >= E) return;
    bool i64 = flags[0] != 0;
    int c = ei[i64 ? 2LL * ((long long)E + e) : (long long)E + e];
    c = clampi(c, 0, n - 1);
    atomicAdd(&cnt[c], 1);
}

// ---- parallel scan: phase 1, per-block (2048-elem) sums ----
__global__ void k_scan_partial(const int* __restrict__ cnt, int* __restrict__ bsum, int n) {
    __shared__ int sdata[256];
    int t = threadIdx.x;
    int base = blockIdx.x * 2048 + t * 8;
    int s = 0;
    #pragma unroll
    for (int j = 0; j < 8; j++) { int idx = base + j; if (idx < n) s += cnt[idx]; }
    sdata[t] = s;
    __syncthreads();
    for (int o = 128; o > 0; o >>= 1) {
        if (t < o) sdata[t] += sdata[t + o];
        __syncthreads();
    }
    if (t == 0) bsum[blockIdx.x] = sdata[0];
}

// ---- phase 2: prefix of bsums + local scan + offs/cursor/dis ----
__global__ void k_scan_final(const int* __restrict__ cnt, const int* __restrict__ bsum,
                             int* __restrict__ offs, int* __restrict__ cursor,
                             float* __restrict__ dis, int n) {
    __shared__ int ssc[256];
    __shared__ int sbase;
    int t = threadIdx.x;
    int blk = blockIdx.x;
    int p = 0;
    for (int j = t; j < blk; j += 256) p += bsum[j];
    ssc[t] = p;
    __syncthreads();
    for (int o = 128; o > 0; o >>= 1) {
        if (t < o) ssc[t] += ssc[t + o];
        __syncthreads();
    }
    if (t == 0) sbase = ssc[0];
    __syncthreads();
    int base = blk * 2048 + t * 8;
    int val[8], loc[8];
    int s = 0;
    #pragma unroll
    for (int j = 0; j < 8; j++) {
        int idx = base + j;
        val[j] = (idx < n) ? cnt[idx] : 0;
        loc[j] = s;
        s += val[j];
    }
    ssc[t] = s;
    __syncthreads();
    for (int o = 1; o < 256; o <<= 1) {
        int v = (t >= o) ? ssc[t - o] : 0;
        __syncthreads();
        ssc[t] += v;
        __syncthreads();
    }
    int excl = (t > 0) ? ssc[t - 1] : 0;
    int b0 = sbase + excl;
    #pragma unroll
    for (int j = 0; j < 8; j++) {
        int idx = base + j;
        if (idx < n) {
            int o = b0 + loc[j];
            offs[idx] = o;
            cursor[idx] = o;
            dis[idx] = rsqrtf(fmaxf((float)(val[j] + 1), 1.0f));
        }
    }
    if (blk == gridDim.x - 1 && t == 255) offs[n] = sbase + ssc[255];
}

__global__ void k_fill(const int* __restrict__ ei, int* __restrict__ cursor,
                       int* __restrict__ csr_row, int E, int n, const int* __restrict__ flags) {
    int e = blockIdx.x * blockDim.x + threadIdx.x;
    if (e >= E) return;
    bool i64 = flags[0] != 0;
    int r = ei[i64 ? 2LL * e : (long long)e];
    int c = ei[i64 ? 2LL * ((long long)E + e) : (long long)E + e];
    r = clampi(r, 0, n - 1);
    c = clampi(c, 0, n - 1);
    int pos = atomicAdd(&cursor[c], 1);
    if (pos >= 0 && pos < E) csr_row[pos] = r;
}

// ---- weight prep: W1t[n][k] bf16 [320][64], W2t[n][k] bf16 [128][320], zero-padded ----
__global__ void k_wtrans(const void* __restrict__ W1, const void* __restrict__ W2,
                         short* __restrict__ W1t, short* __restrict__ W2t,
                         const int* __restrict__ flags) {
    int fbf = flags[1];
    int i = blockIdx.x * blockDim.x + threadIdx.x;
    if (i < 320 * 64) {
        int nn = i >> 6, k = i & 63;
        float v = (nn < 300 && k < 58) ? ld_m<2>(W1, (long long)k * 300 + nn, fbf) : 0.f;
        W1t[i] = f2bf_bits(v);
    }
    int j = i - 320 * 64;
    if (j >= 0 && j < 128 * 320) {
        int nn = j / 320, k = j - nn * 320;
        float v = (nn < 100 && k < 300) ? ld_m<2>(W2, (long long)k * 100 + nn, fbf) : 0.f;
        W2t[j] = f2bf_bits(v);
    }
}

// ---- scalar aggregation (F=1 path, final output) ----
template <int SRCM, int DSTM, bool PRESCALED, bool RELU, bool HAS_BIAS>
__global__ void k_agg1(const void* __restrict__ src, void* __restrict__ dst,
                       const int* __restrict__ offs, const int* __restrict__ csr_row,
                       const float* __restrict__ dis, const void* __restrict__ bias,
                       int n, int E, const int* __restrict__ flags) {
    int i = blockIdx.x * blockDim.x + threadIdx.x;
    if (i >= n) return;
    int fbf = flags[1];
    float di = dis[i];
    float self = ld_m<SRCM>(src, i, fbf);
    float acc = PRESCALED ? self : self * di;
    int e0 = offs[i], e1 = offs[i + 1];
    e0 = clampi(e0, 0, E);
    e1 = clampi(e1, e0, E);
    for (int e = e0; e < e1; ++e) {
        int r = clampi(csr_row[e], 0, n - 1);
        float v = ld_m<SRCM>(src, r, fbf);
        acc += PRESCALED ? v : v * dis[r];
    }
    float out = di * acc;
    if (HAS_BIAS) out += ld_m<2>(bias, 0, fbf);
    if (RELU) out = relu_keepnan(out);
    st_m<DSTM>(dst, i, out, fbf);
}

// ---- paired aggregation w/ 4x-unrolled gather (MLP). DSP threads/node; pairs
// f2<HV aggregated, HV<=f2<DSP zero-fill. SS/DS = src/dst pair strides.
template <int DSP, int HV, int SS, int DS, int SRCM, int DSTM,
          bool PRESCALED, bool RELU, bool HAS_BIAS>
__global__ void k_agg2(const void* __restrict__ src, void* __restrict__ dst,
                       const int* __restrict__ offs, const int* __restrict__ csr_row,
                       const float* __restrict__ dis, const void* __restrict__ bias,
                       int n, int E, const int* __restrict__ flags) {
    long long idx = (long long)blockIdx.x * blockDim.x + threadIdx.x;
    if (idx >= (long long)n * DSP) return;
    int fbf = flags[1];
    int i = (int)(idx / DSP);
    int f2 = (int)(idx - (long long)i * DSP);
    if (f2 >= HV) { st2_m<DSTM>(dst, (long long)i * DS + f2, 0.f, 0.f, fbf); return; }
    float di = dis[i];
    float2 self = ld2_m<SRCM>(src, (long long)i * SS + f2, fbf);
    float ax = PRESCALED ? self.x : self.x * di;
    float ay = PRESCALED ? self.y : self.y * di;
    int e0 = offs[i], e1 = offs[i + 1];
    e0 = clampi(e0, 0, E);
    e1 = clampi(e1, e0, E);
    int e = e0;
    for (; e + 4 <= e1; e += 4) {
        int r0 = clampi(csr_row[e],     0, n - 1);
        int r1 = clampi(csr_row[e + 1], 0, n - 1);
        int r2 = clampi(csr_row[e + 2], 0, n - 1);
        int r3 = clampi(csr_row[e + 3], 0, n - 1);
        float2 v0 = ld2_m<SRCM>(src, (long long)r0 * SS + f2, fbf);
        float2 v1 = ld2_m<SRCM>(src, (long long)r1 * SS + f2, fbf);
        float2 v2 = ld2_m<SRCM>(src, (long long)r2 * SS + f2, fbf);
        float2 v3 = ld2_m<SRCM>(src, (long long)r3 * SS + f2, fbf);
        if (PRESCALED) {
            ax += v0.x + v1.x + v2.x + v3.x;
            ay += v0.y + v1.y + v2.y + v3.y;
        } else {
            float w0 = dis[r0], w1 = dis[r1], w2 = dis[r2], w3 = dis[r3];
            ax = fmaf(v0.x, w0, fmaf(v1.x, w1, fmaf(v2.x, w2, fmaf(v3.x, w3, ax))));
            ay = fmaf(v0.y, w0, fmaf(v1.y, w1, fmaf(v2.y, w2, fmaf(v3.y, w3, ay))));
        }
    }
    for (; e < e1; ++e) {
        int r = clampi(csr_row[e], 0, n - 1);
        float2 v = ld2_m<SRCM>(src, (long long)r * SS + f2, fbf);
        if (PRESCALED) { ax += v.x; ay += v.y; }
        else { float w = dis[r]; ax = fmaf(v.x, w, ax); ay = fmaf(v.y, w, ay); }
    }
    float ox = di * ax, oy = di * ay;
    if (HAS_BIAS) {
        float2 b = ld2_m<2>(bias, f2, fbf);
        ox += b.x; oy += b.y;
    }
    if (RELU) { ox = relu_keepnan(ox); oy = relu_keepnan(oy); }
    st2_m<DSTM>(dst, (long long)i * DS + f2, ox, oy, fbf);
}

// ---- quad aggregation for layer 2: src/dst bf16 compact, QPN quads per node ----
// src stride = dst stride = QPN uint2 (4 bf16 features per quad).
template <int QPN, bool RELU>
__global__ void k_aggq(const uint2* __restrict__ src, uint2* __restrict__ dst,
                       const int* __restrict__ offs, const int* __restrict__ csr_row,
                       const float* __restrict__ dis, const void* __restrict__ bias,
                       int n, int E, const int* __restrict__ flags) {
    long long idx = (long long)blockIdx.x * blockDim.x + threadIdx.x;
    if (idx >= (long long)n * QPN) return;
    int fbf = flags[1];
    int i = (int)(idx / QPN);
    int q = (int)(idx - (long long)i * QPN);
    float di = dis[i];
    uint2 sw = src[(long long)i * QPN + q];
    float a0 = bflo(sw.x), a1 = bfhi(sw.x), a2 = bflo(sw.y), a3 = bfhi(sw.y);
    int e0 = offs[i], e1 = offs[i + 1];
    e0 = clampi(e0, 0, E);
    e1 = clampi(e1, e0, E);
    int e = e0;
    for (; e + 4 <= e1; e += 4) {
        int r0 = clampi(csr_row[e],     0, n - 1);
        int r1 = clampi(csr_row[e + 1], 0, n - 1);
        int r2 = clampi(csr_row[e + 2], 0, n - 1);
        int r3 = clampi(csr_row[e + 3], 0, n - 1);
        uint2 w0 = src[(long long)r0 * QPN + q];
        uint2 w1 = src[(long long)r1 * QPN + q];
        uint2 w2 = src[(long long)r2 * QPN + q];
        uint2 w3 = src[(long long)r3 * QPN + q];
        a0 += bflo(w0.x) + bflo(w1.x) + bflo(w2.x) + bflo(w3.x);
        a1 += bfhi(w0.x) + bfhi(w1.x) + bfhi(w2.x) + bfhi(w3.x);
        a2 += bflo(w0.y) + bflo(w1.y) + bflo(w2.y) + bflo(w3.y);
        a3 += bfhi(w0.y) + bfhi(w1.y) + bfhi(w2.y) + bfhi(w3.y);
    }
    for (; e < e1; ++e) {
        int r = clampi(csr_row[e], 0, n - 1);
        uint2 w = src[(long long)r * QPN + q];
        a0 += bflo(w.x); a1 += bfhi(w.x); a2 += bflo(w.y); a3 += bfhi(w.y);
    }
    float o0 = di * a0 + ld_m<2>(bias, 4 * q + 0, fbf);
    float o1 = di * a1 + ld_m<2>(bias, 4 * q + 1, fbf);
    float o2 = di * a2 + ld_m<2>(bias, 4 * q + 2, fbf);
    float o3 = di * a3 + ld_m<2>(bias, 4 * q + 3, fbf);
    if (RELU) { o0 = relu_keepnan(o0); o1 = relu_keepnan(o1);
                o2 = relu_keepnan(o2); o3 = relu_keepnan(o3); }
    unsigned p0 = ((unsigned)(unsigned short)f2bf_bits(o0)) | (((unsigned)(unsigned short)f2bf_bits(o1)) << 16);
    unsigned p1 = ((unsigned)(unsigned short)f2bf_bits(o2)) | (((unsigned)(unsigned short)f2bf_bits(o3)) << 16);
    dst[(long long)i * QPN + q] = make_uint2(p0, p1);
}

// ---- MFMA bf16 GEMM: C[M][ldc](bf16) = act( A[M][KP](bf16) @ Bt^T * scale + bias ) ----
// A row stride = KP (mult of 32, zero-padded). Bt[n][k] bf16 row stride KP, zero-padded.
// BM=128, BN=NT*16; 4 waves, each 32 rows x BN cols. Writes only gn < ldc.
template <int NT, bool SCALE_ROW, bool HAS_BIAS, bool RELU>
__global__ __launch_bounds__(256) void k_gemm_mfma(
    const ushort* __restrict__ A, const ushort* __restrict__ Bt,
    const void* __restrict__ bias, const float* __restrict__ dis,
    bf16* __restrict__ C, int M, int KP, int chunks, int ldc, int NBreal,
    const int* __restrict__ flags) {
    constexpr int BN = NT * 16;
    __shared__ __align__(16) ushort A_s[128][40];
    __shared__ __align__(16) ushort B_s[BN][40];
    const int t = threadIdx.x;
    const int lane = t & 63;
    const int w = t >> 6;
    const int bm = blockIdx.y * 128;
    const int bn = blockIdx.x * BN;
    const int fbf = flags[1];
    const int mrow = lane & 15;
    const int quad = lane >> 4;

    f4v acc[2][NT];
    #pragma unroll
    for (int a = 0; a < 2; a++)
        #pragma unroll
        for (int b = 0; b < NT; b++)
            #pragma unroll
            for (int r = 0; r < 4; r++) acc[a][b][r] = 0.f;

    for (int c = 0; c < chunks; ++c) {
        const int k0 = c * 32;
        #pragma unroll
        for (int r = 0; r < 2; ++r) {
            int u = t + r * 256;
            int row = u >> 2, kq = (u & 3) * 8;
            int grow = bm + row;
            uint4 v = make_uint4(0u, 0u, 0u, 0u);
            if (grow < M) v = *(const uint4*)(A + (size_t)grow * KP + k0 + kq);
            *(uint4*)&A_s[row][kq] = v;
        }
        for (int u = t; u < BN * 4; u += 256) {
            int row = u >> 2, kq = (u & 3) * 8;
            uint4 v = *(const uint4*)(Bt + (size_t)(bn + row) * KP + k0 + kq);
            *(uint4*)&B_s[row][kq] = v;
        }
        __syncthreads();
        s8v a0 = *(const s8v*)&A_s[w * 32 + mrow][quad * 8];
        s8v a1 = *(const s8v*)&A_s[w * 32 + 16 + mrow][quad * 8];
        #pragma unroll
        for (int nt = 0; nt < NT; ++nt) {
            s8v b = *(const s8v*)&B_s[nt * 16 + mrow][quad * 8];
            acc[0][nt] = __builtin_amdgcn_mfma_f32_16x16x32_bf16(a0, b, acc[0][nt], 0, 0, 0);
            acc[1][nt] = __builtin_amdgcn_mfma_f32_16x16x32_bf16(a1, b, acc[1][nt], 0, 0, 0);
        }
        __syncthreads();
    }
    float sc[2][4];
    #pragma unroll
    for (int mi = 0; mi < 2; ++mi)
        #pragma unroll
        for (int r = 0; r < 4; ++r) {
            int gm = bm + w * 32 + mi * 16 + quad * 4 + r;
            sc[mi][r] = (SCALE_ROW && gm < M) ? dis[gm] : 1.f;
        }
    #pragma unroll
    for (int nt = 0; nt < NT; ++nt) {
        int gn = bn + nt * 16 + mrow;
        if (gn >= ldc) continue;
        float bv = 0.f;
        if (HAS_BIAS) bv = (gn < NBreal) ? ld_m<2>(bias, gn, fbf) : 0.f;
        #pragma unroll
        for (int mi = 0; mi < 2; ++mi)
            #pragma unroll
            for (int r = 0; r < 4; ++r) {
                int gm = bm + w * 32 + mi * 16 + quad * 4 + r;
                if (gm >= M) continue;
                float v = acc[mi][nt][r] * sc[mi][r];
                if (HAS_BIAS) v += bv;
                if (RELU) v = relu_keepnan(v);
                C[(size_t)gm * ldc + gn] = __float2bfloat16(v);
            }
    }
}

// layer-3 GEMV: t3[i] = dis[i] * dot(h2[i,:], W3)
__global__ void k_gemv_w3(const bf16* __restrict__ X, const void* __restrict__ W3,
                          const float* __restrict__ dis, float* __restrict__ t3, int n, int K,
                          const int* __restrict__ flags) {
    int gt = blockIdx.x * blockDim.x + threadIdx.x;
    int w = gt >> 6, lane = gt & 63;
    if (w >= n) return;
    int fbf = flags[1];
    float s = 0.f;
    for (int k = lane; k < K; k += 64)
        s += __bfloat162float(X[(long long)w * K + k]) * ld_m<2>(W3, k, fbf);
    #pragma unroll
    for (int o = 32; o; o >>= 1) s += __shfl_down(s, o, 64);
    if (lane == 0) t3[w] = dis[w] * s;
}

extern "C" void kernel_launch(void* const* d_in, const int* in_sizes, int n_in,
                              void* d_out, int out_size, void* d_ws, size_t ws_size,
                              hipStream_t stream) {
    const void* x  = d_in[0];
    const int*  ei = (const int*)d_in[1];
    const void* W1 = d_in[2];
    const void* b1 = d_in[3];
    const void* W2 = d_in[4];
    const void* b2 = d_in[5];
    const void* W3 = d_in[6];
    const void* b3 = d_in[7];

    const int F0 = 58, F1 = 300, F2 = 100;
    const int N = in_sizes[0] / F0;
    const int E = in_sizes[1] / 2;
    const int nb = (N + 2047) / 2048;
    const int gy = (N + 127) / 128;

    size_t off = 0;
    auto alloc = [&](size_t bytes) -> void* {
        void* p = (char*)d_ws + off;
        off = (off + bytes + 255) & ~(size_t)255;
        return p;
    };
    int*   flags   = (int*)alloc(256);
    int*   cnt     = (int*)alloc((size_t)N * 4);
    int*   offs    = (int*)alloc((size_t)(N + 1) * 4);
    int*   cursor  = (int*)alloc((size_t)N * 4);
    float* dis     = (float*)alloc((size_t)N * 4);
    int*   bsum    = (int*)alloc((size_t)nb * 4);
    int*   csr_row = (int*)alloc((size_t)E * 4);
    short* W1t     = (short*)alloc((size_t)320 * 64 * 2);
    short* W2t     = (short*)alloc((size_t)128 * 320 * 2);
    // region A: z_bf [N][64] bf16 (12.8MB) -> t2 [N][100] bf16 compact (20MB) -> t3 [N] f32
    void*  regA    = alloc((size_t)N * 128 * 2);
    ushort* z_bf = (ushort*)regA;
    bf16*   t2   = (bf16*)regA;
    float*  t3   = (float*)regA;
    // region B: h1 [N][320] bf16 (64MB) -> h2 [N][100] bf16 compact (20MB)
    void*  regB    = alloc((size_t)N * 320 * 2);
    bf16*  h1 = (bf16*)regB;
    bf16*  h2 = (bf16*)regB;

    // ---- CSR build + dis + dtype detection + weight prep ----
    k_init<<<1024, 256, 0, stream>>>(cnt, N, csr_row, E, ei, (const unsigned*)x, flags);
    k_count<<<(E + 255) / 256, 256, 0, stream>>>(ei, cnt, E, N, flags);
    k_scan_partial<<<nb, 256, 0, stream>>>(cnt, bsum, N);
    k_scan_final<<<nb, 256, 0, stream>>>(cnt, bsum, offs, cursor, dis, N);
    k_fill<<<(E + 255) / 256, 256, 0, stream>>>(ei, cursor, csr_row, E, N, flags);
    k_wtrans<<<(320 * 64 + 128 * 320 + 255) / 256, 256, 0, stream>>>(W1, W2, W1t, W2t, flags);

    // ---- layer 1: aggregate x at width 58 -> z_bf [N][64] (pad zeroed), then MFMA GEMM ----
    k_agg2<32, 29, 29, 32, 2, 1, false, false, false>
        <<<((long long)N * 32 + 255) / 256, 256, 0, stream>>>(
        x, z_bf, offs, csr_row, dis, nullptr, N, E, flags);
    k_gemm_mfma<4, false, true, true><<<dim3(5, gy), 256, 0, stream>>>(
        z_bf, (const ushort*)W1t, b1, dis, h1, N, 64, 2, 320, 300, flags);

    // ---- layer 2: MFMA GEMM (row-prescaled) -> t2 [N][100] compact, then aggregate ----
    k_gemm_mfma<8, true, false, false><<<dim3(1, gy), 256, 0, stream>>>(
        (const ushort*)h1, (const ushort*)W2t, nullptr, dis, t2, N, 320, 10, 100, 0, flags);
    k_aggq<25, true><<<((long long)N * 25 + 255) / 256, 256, 0, stream>>>(
        (const uint2*)t2, (uint2*)h2, offs, csr_row, dis, b2, N, E, flags);

    // ---- layer 3: GEMV (row-prescaled), then aggregate into output ----
    k_gemv_w3<<<((long long)N * 64 + 255) / 256, 256, 0, stream>>>(h2, W3, dis, t3, N, F2, flags);
    k_agg1<0, 2, true, false, true><<<(N + 255) / 256, 256, 0, stream>>>(
        t3, d_out, offs, csr_row, dis, b3, N, E, flags);
}

// Round 8
// 398.043 us; speedup vs baseline: 2.8458x; 1.0701x over previous
//
#include <hip/hip_runtime.h>
#include <hip/hip_bf16.h>

typedef __hip_bfloat16 bf16;
typedef __attribute__((ext_vector_type(8))) short s8v;   // 8 bf16 = 4 VGPRs (MFMA A/B frag)
typedef __attribute__((ext_vector_type(4))) float f4v;   // 4 f32 (MFMA C/D frag)

// MODE: 0 = f32 fixed, 1 = bf16 fixed, 2 = dynamic (per flags[1])
template <int MODE>
__device__ __forceinline__ float ld_m(const void* p, long long i, int dynbf) {
    if (MODE == 0) return ((const float*)p)[i];
    if (MODE == 1) return __bfloat162float(((const bf16*)p)[i]);
    return dynbf ? __bfloat162float(((const bf16*)p)[i]) : ((const float*)p)[i];
}
template <int MODE>
__device__ __forceinline__ void st_m(void* p, long long i, float v, int dynbf) {
    if (MODE == 0) { ((float*)p)[i] = v; return; }
    if (MODE == 1) { ((bf16*)p)[i] = __float2bfloat16(v); return; }
    if (dynbf) ((bf16*)p)[i] = __float2bfloat16(v);
    else       ((float*)p)[i] = v;
}

__device__ __forceinline__ float relu_keepnan(float v) { return (v <= 0.f) ? 0.f : v; }
__device__ __forceinline__ int clampi(int v, int lo, int hi) {
    return v < lo ? lo : (v > hi ? hi : v);
}
__device__ __forceinline__ short f2bf_bits(float v) {
    bf16 h = __float2bfloat16(v);
    return *(short*)&h;
}
__device__ __forceinline__ float bflo(unsigned w) { return __uint_as_float(w << 16); }
__device__ __forceinline__ float bfhi(unsigned w) { return __uint_as_float(w & 0xffff0000u); }
__device__ __forceinline__ unsigned pack2(float a, float b) {
    return ((unsigned)(unsigned short)f2bf_bits(a)) | (((unsigned)(unsigned short)f2bf_bits(b)) << 16);
}

// ---- init: zero cnt; detect edge int64 (flags[0]) and float bf16 (flags[1]) ----
__global__ void k_init(int* __restrict__ cnt, int n,
                       const int* __restrict__ ei, const unsigned* __restrict__ xw,
                       int* __restrict__ flags) {
    int i = blockIdx.x * blockDim.x + threadIdx.x;
    int stride = gridDim.x * blockDim.x;
    for (int j = i; j < n; j += stride) cnt[j] = 0;
    if (blockIdx.x == 0 && threadIdx.x < 64) {
        int lane = threadIdx.x;
        int ov = (lane < 16) ? ei[2 * lane + 1] : 0;
        unsigned long long be = __ballot(ov != 0);
        int inb = 0;
        #pragma unroll
        for (int q = 0; q < 2; ++q) {
            unsigned w = xw[lane + 64 * q];
            int e = (w >> 7) & 0xFF;
            inb += (e >= 110 && e <= 131) ? 1 : 0;
        }
        #pragma unroll
        for (int o = 32; o; o >>= 1) inb += __shfl_down(inb, o, 64);
        if (lane == 0) {
            flags[0] = (be == 0ULL) ? 1 : 0;   // edges are int64
            flags[1] = (inb >= 64) ? 1 : 0;    // floats are bf16
        }
    }
}

__global__ void k_count(const int* __restrict__ ei, int* __restrict__ cnt,
                        int E, int n, const int* __restrict__ flags) {
    int e = blockIdx.x * blockDim.x + threadIdx.x;
    if (e >= E) return;
    bool i64 = flags[0] != 0;
    int c = ei[i64 ? 2LL * ((long long)E + e) : (long long)E + e];
    c = clampi(c, 0, n - 1);
    atomicAdd(&cnt[c], 1);
}

// ---- parallel scan: phase 1, per-block (2048-elem) sums ----
__global__ void k_scan_partial(const int* __restrict__ cnt, int* __restrict__ bsum, int n) {
    __shared__ int sdata[256];
    int t = threadIdx.x;
    int base = blockIdx.x * 2048 + t * 8;
    int s = 0;
    #pragma unroll
    for (int j = 0; j < 8; j++) { int idx = base + j; if (idx < n) s += cnt[idx]; }
    sdata[t] = s;
    __syncthreads();
    for (int o = 128; o > 0; o >>= 1) {
        if (t < o) sdata[t] += sdata[t + o];
        __syncthreads();
    }
    if (t == 0) bsum[blockIdx.x] = sdata[0];
}

// ---- phase 2: prefix of bsums + local scan + offs/cursor/dis ----
__global__ void k_scan_final(const int* __restrict__ cnt, const int* __restrict__ bsum,
                             int* __restrict__ offs, int* __restrict__ cursor,
                             float* __restrict__ dis, int n) {
    __shared__ int ssc[256];
    __shared__ int sbase;
    int t = threadIdx.x;
    int blk = blockIdx.x;
    int p = 0;
    for (int j = t; j < blk; j += 256) p += bsum[j];
    ssc[t] = p;
    __syncthreads();
    for (int o = 128; o > 0; o >>= 1) {
        if (t < o) ssc[t] += ssc[t + o];
        __syncthreads();
    }
    if (t == 0) sbase = ssc[0];
    __syncthreads();
    int base = blk * 2048 + t * 8;
    int val[8], loc[8];
    int s = 0;
    #pragma unroll
    for (int j = 0; j < 8; j++) {
        int idx = base + j;
        val[j] = (idx < n) ? cnt[idx] : 0;
        loc[j] = s;
        s += val[j];
    }
    ssc[t] = s;
    __syncthreads();
    for (int o = 1; o < 256; o <<= 1) {
        int v = (t >= o) ? ssc[t - o] : 0;
        __syncthreads();
        ssc[t] += v;
        __syncthreads();
    }
    int excl = (t > 0) ? ssc[t - 1] : 0;
    int b0 = sbase + excl;
    #pragma unroll
    for (int j = 0; j < 8; j++) {
        int idx = base + j;
        if (idx < n) {
            int o = b0 + loc[j];
            offs[idx] = o;
            cursor[idx] = o;
            dis[idx] = rsqrtf(fmaxf((float)(val[j] + 1), 1.0f));
        }
    }
    if (blk == gridDim.x - 1 && t == 255) offs[n] = sbase + ssc[255];
}

// ---- fill: non-temporal scatter (random 4B writes; avoid L2 line writeback amp) ----
__global__ void k_fill(const int* __restrict__ ei, int* __restrict__ cursor,
                       int* __restrict__ csr_row, int E, int n, const int* __restrict__ flags) {
    int e = blockIdx.x * blockDim.x + threadIdx.x;
    if (e >= E) return;
    bool i64 = flags[0] != 0;
    int r = ei[i64 ? 2LL * e : (long long)e];
    int c = ei[i64 ? 2LL * ((long long)E + e) : (long long)E + e];
    r = clampi(r, 0, n - 1);
    c = clampi(c, 0, n - 1);
    int pos = atomicAdd(&cursor[c], 1);
    if (pos >= 0 && pos < E) __builtin_nontemporal_store(r, &csr_row[pos]);
}

// ---- weight prep: W1t[n][k] bf16 [320][64], W2t[n][k] bf16 [128][320], zero-padded ----
__global__ void k_wtrans(const void* __restrict__ W1, const void* __restrict__ W2,
                         short* __restrict__ W1t, short* __restrict__ W2t,
                         const int* __restrict__ flags) {
    int fbf = flags[1];
    int i = blockIdx.x * blockDim.x + threadIdx.x;
    if (i < 320 * 64) {
        int nn = i >> 6, k = i & 63;
        float v = (nn < 300 && k < 58) ? ld_m<2>(W1, (long long)k * 300 + nn, fbf) : 0.f;
        W1t[i] = f2bf_bits(v);
    }
    int j = i - 320 * 64;
    if (j >= 0 && j < 128 * 320) {
        int nn = j / 320, k = j - nn * 320;
        float v = (nn < 100 && k < 300) ? ld_m<2>(W2, (long long)k * 100 + nn, fbf) : 0.f;
        W2t[j] = f2bf_bits(v);
    }
}

// ---- x conversion: x[N][58] (dyn dtype) -> xq[N][64] bf16, zero-padded ----
__global__ void k_cvt_x(const void* __restrict__ x, ushort* __restrict__ xq, int n,
                        const int* __restrict__ flags) {
    int fbf = flags[1];
    long long idx = (long long)blockIdx.x * blockDim.x + threadIdx.x;
    if (idx >= (long long)n * 64) return;
    int i = (int)(idx >> 6), f = (int)(idx & 63);
    float v = (f < 58) ? ld_m<2>(x, (long long)i * 58 + f, fbf) : 0.f;
    xq[idx] = (ushort)f2bf_bits(v);
}

// ---- layer-1 quad aggregation (NOT prescaled): z = di*(di*x_i + sum dis[r]*x_r) ----
// src/dst: bf16 quads, row stride QPN quads. Zero pads propagate naturally.
template <int QPN>
__global__ void k_aggq_pre(const uint2* __restrict__ src, uint2* __restrict__ dst,
                           const int* __restrict__ offs, const int* __restrict__ csr_row,
                           const float* __restrict__ dis, int n, int E) {
    long long idx = (long long)blockIdx.x * blockDim.x + threadIdx.x;
    if (idx >= (long long)n * QPN) return;
    int i = (int)(idx / QPN);
    int q = (int)(idx - (long long)i * QPN);
    float di = dis[i];
    uint2 sw = src[(long long)i * QPN + q];
    float a0 = bflo(sw.x) * di, a1 = bfhi(sw.x) * di;
    float a2 = bflo(sw.y) * di, a3 = bfhi(sw.y) * di;
    int e0 = offs[i], e1 = offs[i + 1];
    e0 = clampi(e0, 0, E);
    e1 = clampi(e1, e0, E);
    int e = e0;
    for (; e + 4 <= e1; e += 4) {
        int r0 = clampi(csr_row[e],     0, n - 1);
        int r1 = clampi(csr_row[e + 1], 0, n - 1);
        int r2 = clampi(csr_row[e + 2], 0, n - 1);
        int r3 = clampi(csr_row[e + 3], 0, n - 1);
        uint2 w0 = src[(long long)r0 * QPN + q];
        uint2 w1 = src[(long long)r1 * QPN + q];
        uint2 w2 = src[(long long)r2 * QPN + q];
        uint2 w3 = src[(long long)r3 * QPN + q];
        float d0 = dis[r0], d1 = dis[r1], d2 = dis[r2], d3 = dis[r3];
        a0 = fmaf(bflo(w0.x), d0, fmaf(bflo(w1.x), d1, fmaf(bflo(w2.x), d2, fmaf(bflo(w3.x), d3, a0))));
        a1 = fmaf(bfhi(w0.x), d0, fmaf(bfhi(w1.x), d1, fmaf(bfhi(w2.x), d2, fmaf(bfhi(w3.x), d3, a1))));
        a2 = fmaf(bflo(w0.y), d0, fmaf(bflo(w1.y), d1, fmaf(bflo(w2.y), d2, fmaf(bflo(w3.y), d3, a2))));
        a3 = fmaf(bfhi(w0.y), d0, fmaf(bfhi(w1.y), d1, fmaf(bfhi(w2.y), d2, fmaf(bfhi(w3.y), d3, a3))));
    }
    for (; e < e1; ++e) {
        int r = clampi(csr_row[e], 0, n - 1);
        uint2 w = src[(long long)r * QPN + q];
        float d = dis[r];
        a0 = fmaf(bflo(w.x), d, a0);
        a1 = fmaf(bfhi(w.x), d, a1);
        a2 = fmaf(bflo(w.y), d, a2);
        a3 = fmaf(bfhi(w.y), d, a3);
    }
    dst[(long long)i * QPN + q] = make_uint2(pack2(di * a0, di * a1), pack2(di * a2, di * a3));
}

// ---- layer-2 aggregation FUSED with layer-3 GEMV ----
// 32 threads/node (q<QPN=25 active). Computes h2 quad = relu(di*sum + b2), dots with
// W3 quad, LDS-reduces 25 partials -> t3[node] = di_node_NOT...  t3[i] = dis[i]*dot(h2_i,W3).
template <int QPN>
__global__ void k_aggq_fused(const uint2* __restrict__ src, float* __restrict__ t3,
                             const int* __restrict__ offs, const int* __restrict__ csr_row,
                             const float* __restrict__ dis, const void* __restrict__ b2,
                             const void* __restrict__ W3, int n, int E,
                             const int* __restrict__ flags) {
    __shared__ float sdata[256];
    int tid = threadIdx.x;
    long long gidx = (long long)blockIdx.x * 256 + tid;
    int node = (int)(gidx >> 5);
    int q = (int)(gidx & 31);
    int fbf = flags[1];
    float partial = 0.f;
    float di = 0.f;
    if (node < n) di = dis[node];
    if (node < n && q < QPN) {
        uint2 sw = src[(long long)node * QPN + q];
        float a0 = bflo(sw.x), a1 = bfhi(sw.x), a2 = bflo(sw.y), a3 = bfhi(sw.y);
        int e0 = offs[node], e1 = offs[node + 1];
        e0 = clampi(e0, 0, E);
        e1 = clampi(e1, e0, E);
        int e = e0;
        for (; e + 4 <= e1; e += 4) {
            int r0 = clampi(csr_row[e],     0, n - 1);
            int r1 = clampi(csr_row[e + 1], 0, n - 1);
            int r2 = clampi(csr_row[e + 2], 0, n - 1);
            int r3 = clampi(csr_row[e + 3], 0, n - 1);
            uint2 w0 = src[(long long)r0 * QPN + q];
            uint2 w1 = src[(long long)r1 * QPN + q];
            uint2 w2 = src[(long long)r2 * QPN + q];
            uint2 w3 = src[(long long)r3 * QPN + q];
            a0 += bflo(w0.x) + bflo(w1.x) + bflo(w2.x) + bflo(w3.x);
            a1 += bfhi(w0.x) + bfhi(w1.x) + bfhi(w2.x) + bfhi(w3.x);
            a2 += bflo(w0.y) + bflo(w1.y) + bflo(w2.y) + bflo(w3.y);
            a3 += bfhi(w0.y) + bfhi(w1.y) + bfhi(w2.y) + bfhi(w3.y);
        }
        for (; e < e1; ++e) {
            int r = clampi(csr_row[e], 0, n - 1);
            uint2 w = src[(long long)r * QPN + q];
            a0 += bflo(w.x); a1 += bfhi(w.x); a2 += bflo(w.y); a3 += bfhi(w.y);
        }
        float o0 = relu_keepnan(di * a0 + ld_m<2>(b2, 4 * q + 0, fbf));
        float o1 = relu_keepnan(di * a1 + ld_m<2>(b2, 4 * q + 1, fbf));
        float o2 = relu_keepnan(di * a2 + ld_m<2>(b2, 4 * q + 2, fbf));
        float o3 = relu_keepnan(di * a3 + ld_m<2>(b2, 4 * q + 3, fbf));
        partial = o0 * ld_m<2>(W3, 4 * q + 0, fbf) + o1 * ld_m<2>(W3, 4 * q + 1, fbf)
                + o2 * ld_m<2>(W3, 4 * q + 2, fbf) + o3 * ld_m<2>(W3, 4 * q + 3, fbf);
    }
    sdata[tid] = partial;
    __syncthreads();
    if (q == 0 && node < n) {
        float s = 0.f;
        #pragma unroll
        for (int j = 0; j < QPN; ++j) s += sdata[tid + j];
        t3[node] = di * s;
    }
}

// ---- scalar aggregation (final output; src=t3 f32 prescaled) ----
template <int SRCM, int DSTM, bool PRESCALED, bool RELU, bool HAS_BIAS>
__global__ void k_agg1(const void* __restrict__ src, void* __restrict__ dst,
                       const int* __restrict__ offs, const int* __restrict__ csr_row,
                       const float* __restrict__ dis, const void* __restrict__ bias,
                       int n, int E, const int* __restrict__ flags) {
    int i = blockIdx.x * blockDim.x + threadIdx.x;
    if (i >= n) return;
    int fbf = flags[1];
    float di = dis[i];
    float self = ld_m<SRCM>(src, i, fbf);
    float acc = PRESCALED ? self : self * di;
    int e0 = offs[i], e1 = offs[i + 1];
    e0 = clampi(e0, 0, E);
    e1 = clampi(e1, e0, E);
    int e = e0;
    for (; e + 4 <= e1; e += 4) {
        int r0 = clampi(csr_row[e],     0, n - 1);
        int r1 = clampi(csr_row[e + 1], 0, n - 1);
        int r2 = clampi(csr_row[e + 2], 0, n - 1);
        int r3 = clampi(csr_row[e + 3], 0, n - 1);
        acc += ld_m<SRCM>(src, r0, fbf) + ld_m<SRCM>(src, r1, fbf)
             + ld_m<SRCM>(src, r2, fbf) + ld_m<SRCM>(src, r3, fbf);
    }
    for (; e < e1; ++e) {
        int r = clampi(csr_row[e], 0, n - 1);
        acc += ld_m<SRCM>(src, r, fbf);
    }
    float out = di * acc;
    if (HAS_BIAS) out += ld_m<2>(bias, 0, fbf);
    if (RELU) out = relu_keepnan(out);
    st_m<DSTM>(dst, i, out, fbf);
}

// ---- MFMA bf16 GEMM: C[M][ldc](bf16) = act( A[M][KP](bf16) @ Bt^T * scale + bias ) ----
template <int NT, bool SCALE_ROW, bool HAS_BIAS, bool RELU>
__global__ __launch_bounds__(256) void k_gemm_mfma(
    const ushort* __restrict__ A, const ushort* __restrict__ Bt,
    const void* __restrict__ bias, const float* __restrict__ dis,
    bf16* __restrict__ C, int M, int KP, int chunks, int ldc, int NBreal,
    const int* __restrict__ flags) {
    constexpr int BN = NT * 16;
    __shared__ __align__(16) ushort A_s[128][40];
    __shared__ __align__(16) ushort B_s[BN][40];
    const int t = threadIdx.x;
    const int lane = t & 63;
    const int w = t >> 6;
    const int bm = blockIdx.y * 128;
    const int bn = blockIdx.x * BN;
    const int fbf = flags[1];
    const int mrow = lane & 15;
    const int quad = lane >> 4;

    f4v acc[2][NT];
    #pragma unroll
    for (int a = 0; a < 2; a++)
        #pragma unroll
        for (int b = 0; b < NT; b++)
            #pragma unroll
            for (int r = 0; r < 4; r++) acc[a][b][r] = 0.f;

    for (int c = 0; c < chunks; ++c) {
        const int k0 = c * 32;
        #pragma unroll
        for (int r = 0; r < 2; ++r) {
            int u = t + r * 256;
            int row = u >> 2, kq = (u & 3) * 8;
            int grow = bm + row;
            uint4 v = make_uint4(0u, 0u, 0u, 0u);
            if (grow < M) v = *(const uint4*)(A + (size_t)grow * KP + k0 + kq);
            *(uint4*)&A_s[row][kq] = v;
        }
        for (int u = t; u < BN * 4; u += 256) {
            int row = u >> 2, kq = (u & 3) * 8;
            uint4 v = *(const uint4*)(Bt + (size_t)(bn + row) * KP + k0 + kq);
            *(uint4*)&B_s[row][kq] = v;
        }
        __syncthreads();
        s8v a0 = *(const s8v*)&A_s[w * 32 + mrow][quad * 8];
        s8v a1 = *(const s8v*)&A_s[w * 32 + 16 + mrow][quad * 8];
        #pragma unroll
        for (int nt = 0; nt < NT; ++nt) {
            s8v b = *(const s8v*)&B_s[nt * 16 + mrow][quad * 8];
            acc[0][nt] = __builtin_amdgcn_mfma_f32_16x16x32_bf16(a0, b, acc[0][nt], 0, 0, 0);
            acc[1][nt] = __builtin_amdgcn_mfma_f32_16x16x32_bf16(a1, b, acc[1][nt], 0, 0, 0);
        }
        __syncthreads();
    }
    float sc[2][4];
    #pragma unroll
    for (int mi = 0; mi < 2; ++mi)
        #pragma unroll
        for (int r = 0; r < 4; ++r) {
            int gm = bm + w * 32 + mi * 16 + quad * 4 + r;
            sc[mi][r] = (SCALE_ROW && gm < M) ? dis[gm] : 1.f;
        }
    #pragma unroll
    for (int nt = 0; nt < NT; ++nt) {
        int gn = bn + nt * 16 + mrow;
        if (gn >= ldc) continue;
        float bv = 0.f;
        if (HAS_BIAS) bv = (gn < NBreal) ? ld_m<2>(bias, gn, fbf) : 0.f;
        #pragma unroll
        for (int mi = 0; mi < 2; ++mi)
            #pragma unroll
            for (int r = 0; r < 4; ++r) {
                int gm = bm + w * 32 + mi * 16 + quad * 4 + r;
                if (gm >= M) continue;
                float v = acc[mi][nt][r] * sc[mi][r];
                if (HAS_BIAS) v += bv;
                if (RELU) v = relu_keepnan(v);
                C[(size_t)gm * ldc + gn] = __float2bfloat16(v);
            }
    }
}

extern "C" void kernel_launch(void* const* d_in, const int* in_sizes, int n_in,
                              void* d_out, int out_size, void* d_ws, size_t ws_size,
                              hipStream_t stream) {
    const void* x  = d_in[0];
    const int*  ei = (const int*)d_in[1];
    const void* W1 = d_in[2];
    const void* b1 = d_in[3];
    const void* W2 = d_in[4];
    const void* b2 = d_in[5];
    const void* W3 = d_in[6];
    const void* b3 = d_in[7];

    const int F0 = 58;
    const int N = in_sizes[0] / F0;
    const int E = in_sizes[1] / 2;
    const int nb = (N + 2047) / 2048;
    const int gy = (N + 127) / 128;

    size_t off = 0;
    auto alloc = [&](size_t bytes) -> void* {
        void* p = (char*)d_ws + off;
        off = (off + bytes + 255) & ~(size_t)255;
        return p;
    };
    int*   flags   = (int*)alloc(256);
    int*   cnt     = (int*)alloc((size_t)N * 4);
    int*   offs    = (int*)alloc((size_t)(N + 1) * 4);
    int*   cursor  = (int*)alloc((size_t)N * 4);
    float* dis     = (float*)alloc((size_t)N * 4);
    int*   bsum    = (int*)alloc((size_t)nb * 4);
    int*   csr_row = (int*)alloc((size_t)E * 4);
    short* W1t     = (short*)alloc((size_t)320 * 64 * 2);
    short* W2t     = (short*)alloc((size_t)128 * 320 * 2);
    float* t3      = (float*)alloc((size_t)N * 4);
    // region A: z_bf [N][64] bf16 (12.8MB) -> t2 [N][100] bf16 compact (20MB)
    void*  regA    = alloc((size_t)N * 128 * 2);
    ushort* z_bf = (ushort*)regA;
    bf16*   t2   = (bf16*)regA;
    // region B: xq [N][64] bf16 (12.8MB) -> h1 [N][320] bf16 (64MB); xq dead before h1 written
    void*  regB    = alloc((size_t)N * 320 * 2);
    ushort* xq = (ushort*)regB;
    bf16*   h1 = (bf16*)regB;

    // ---- CSR build + dis + dtype detection + weight/x prep ----
    k_init<<<1024, 256, 0, stream>>>(cnt, N, ei, (const unsigned*)x, flags);
    k_count<<<(E + 255) / 256, 256, 0, stream>>>(ei, cnt, E, N, flags);
    k_scan_partial<<<nb, 256, 0, stream>>>(cnt, bsum, N);
    k_scan_final<<<nb, 256, 0, stream>>>(cnt, bsum, offs, cursor, dis, N);
    k_fill<<<(E + 255) / 256, 256, 0, stream>>>(ei, cursor, csr_row, E, N, flags);
    k_wtrans<<<(320 * 64 + 128 * 320 + 255) / 256, 256, 0, stream>>>(W1, W2, W1t, W2t, flags);
    k_cvt_x<<<((long long)N * 64 + 255) / 256, 256, 0, stream>>>(x, xq, N, flags);

    // ---- layer 1: quad-aggregate xq -> z_bf [N][64], then MFMA GEMM -> h1 ----
    k_aggq_pre<16><<<((long long)N * 16 + 255) / 256, 256, 0, stream>>>(
        (const uint2*)xq, (uint2*)z_bf, offs, csr_row, dis, N, E);
    k_gemm_mfma<4, false, true, true><<<dim3(5, gy), 256, 0, stream>>>(
        z_bf, (const ushort*)W1t, b1, dis, h1, N, 64, 2, 320, 300, flags);

    // ---- layer 2: MFMA GEMM (row-prescaled) -> t2 [N][100], then fused agg+GEMV -> t3 ----
    k_gemm_mfma<8, true, false, false><<<dim3(1, gy), 256, 0, stream>>>(
        (const ushort*)h1, (const ushort*)W2t, nullptr, dis, t2, N, 320, 10, 100, 0, flags);
    k_aggq_fused<25><<<((long long)N * 32 + 255) / 256, 256, 0, stream>>>(
        (const uint2*)t2, t3, offs, csr_row, dis, b2, W3, N, E, flags);

    // ---- layer 3: aggregate t3 into output ----
    k_agg1<0, 2, true, false, true><<<(N + 255) / 256, 256, 0, stream>>>(
        t3, d_out, offs, csr_row, dis, b3, N, E, flags);
}